// Round 1
// baseline (324.863 us; speedup 1.0000x reference)
//
#include <hip/hip_runtime.h>
#include <cstddef>

#define TT 16384
#define NFRAMES 513
#define BNT 4104              // 8 * 513
#define PI32 0.09817477042468103870f   // pi/32

// ---------------------------------------------------------------------------
// K1: STFT.  x[b][ch][t] -> U[fc][ch][bn],  fc = 2f+c (re/im interleaved rows),
// bn = b*513 + n.  Windowed frames (reflect pad) staged in LDS, then a
// frames(64) x j(64) @ j(64) x fc(64) register-tiled GEMM; f=32 handled in an
// epilogue (its imag bin is identically zero).
// ---------------------------------------------------------------------------
__global__ __launch_bounds__(256) void k1_stft(const float* __restrict__ x,
                                               float* __restrict__ U) {
  const int tile = blockIdx.x;   // 0..8  (frame tiles of 64; last has 1 frame)
  const int ch   = blockIdx.y;   // input channel
  const int b    = blockIdx.z;
  const int F0 = tile * 64;
  const int nf = min(64, NFRAMES - F0);
  const int tid = threadIdx.x;

  __shared__ float xseg[2080];       // padded-signal segment
  __shared__ float Aw[64 * 66];      // [j][fl] windowed frames, stride 66 (pad)
  __shared__ float Bm[64 * 64];      // [j][fc] DFT matrix, fc<64 (f<32)

  const float* xb = x + (size_t)(b * 64 + ch) * TT;
  const int nseg = 32 * nf + 32;
  for (int s = tid; s < nseg; s += 256) {
    int t = 32 * F0 + s - 32;        // reflect padding (PAD=32)
    if (t < 0) t = -t;
    if (t >= TT) t = 2 * TT - 2 - t;
    xseg[s] = xb[t];
  }
  for (int idx = tid; idx < 64 * 64; idx += 256) {
    const int j = idx >> 6, fc = idx & 63;
    const int f = fc >> 1;
    const float ang = (float)((f * j) & 63) * PI32;
    Bm[idx] = (fc & 1) ? -sinf(ang) : cosf(ang);   // U = sum v * e^{-i2pi f j/64}
  }
  __syncthreads();
  for (int idx = tid; idx < 64 * 64; idx += 256) {
    const int j = idx >> 6, fl = idx & 63;
    const float wj = 0.5f * (1.0f - cosf((float)j * PI32));  // periodic Hann
    Aw[j * 66 + fl] = (fl < nf) ? wj * xseg[32 * fl + j] : 0.0f;
  }
  __syncthreads();

  // thread tile: 2 frames x 8 fc
  const int fl0 = 2 * (tid >> 3);
  const int fc0 = 8 * (tid & 7);
  float a0[8], a1[8];
#pragma unroll
  for (int k = 0; k < 8; ++k) { a0[k] = 0.f; a1[k] = 0.f; }
#pragma unroll 8
  for (int j = 0; j < 64; ++j) {
    const float2 av = *(const float2*)&Aw[j * 66 + fl0];
    const float4 b0 = *(const float4*)&Bm[j * 64 + fc0];
    const float4 b1 = *(const float4*)&Bm[j * 64 + fc0 + 4];
    const float bv[8] = {b0.x, b0.y, b0.z, b0.w, b1.x, b1.y, b1.z, b1.w};
#pragma unroll
    for (int k = 0; k < 8; ++k) {
      a0[k] = fmaf(av.x, bv[k], a0[k]);
      a1[k] = fmaf(av.y, bv[k], a1[k]);
    }
  }
  const int bnb = b * NFRAMES + F0;
  if (fl0 < nf) {
    const bool second = (fl0 + 1 < nf);
#pragma unroll
    for (int k = 0; k < 8; ++k) {
      float* p = U + (size_t)((fc0 + k) * 64 + ch) * BNT + bnb + fl0;
      p[0] = a0[k];
      if (second) p[1] = a1[k];
    }
  }
  // epilogue: f=32 -> real = sum_j (-1)^j * Aw[j], imag = 0 exactly
  if (tid < 64 && tid < nf) {
    const int fl = tid;
    float s = 0.f;
#pragma unroll 8
    for (int j = 0; j < 64; ++j) {
      const float v = Aw[j * 66 + fl];
      s = (j & 1) ? (s - v) : (s + v);
    }
    U[(size_t)(64 * 64 + ch) * BNT + bnb + fl] = s;
    U[(size_t)(65 * 64 + ch) * BNT + bnb + fl] = 0.f;
  }
}

// ---------------------------------------------------------------------------
// K2: channel mix, IN PLACE over U.  For each f (33) and bn-tile (128):
//   Y[2f+c][o][bn] = sum_i W[o][i][f] * U[2f+c][i][bn]
// WG loads its exclusive (rows 2f,2f+1) x (bn tile) region to LDS, computes,
// writes back to the same global region (no cross-WG overlap).
// ---------------------------------------------------------------------------
__global__ __launch_bounds__(256) void k2_mix(const float* __restrict__ Wt,
                                              float* __restrict__ U) {
  const int f   = blockIdx.y;         // 0..32
  const int bn0 = blockIdx.x * 128;   // 33 tiles; last has 8 valid
  const int nb  = min(128, BNT - bn0);
  const int tid = threadIdx.x;
  __shared__ float Ush[2 * 64 * 128];   // [c][i][q]  64 KB
  __shared__ float Wl[64 * 64];         // [i][o]     16 KB

  for (int idx = tid; idx < 2 * 64 * 128; idx += 256) {
    const int c = idx >> 13, i = (idx >> 7) & 63, q = idx & 127;
    Ush[idx] = (q < nb) ? U[(size_t)((2 * f + c) * 64 + i) * BNT + bn0 + q] : 0.f;
  }
  for (int idx = tid; idx < 64 * 64; idx += 256) {
    const int i = idx >> 6, o = idx & 63;
    Wl[idx] = Wt[(size_t)(o * 64 + i) * 33 + f];
  }
  __syncthreads();

  // thread tile: 4 o x 8 bn x {re,im}
  const int o0 = 4 * (tid >> 4);
  const int q0 = 8 * (tid & 15);
  float ar[4][8], ai[4][8];
#pragma unroll
  for (int a = 0; a < 4; ++a)
#pragma unroll
    for (int k = 0; k < 8; ++k) { ar[a][k] = 0.f; ai[a][k] = 0.f; }

#pragma unroll 8
  for (int i = 0; i < 64; ++i) {
    const float4 wv = *(const float4*)&Wl[i * 64 + o0];
    const float4 r0 = *(const float4*)&Ush[i * 128 + q0];
    const float4 r1 = *(const float4*)&Ush[i * 128 + q0 + 4];
    const float4 m0 = *(const float4*)&Ush[8192 + i * 128 + q0];
    const float4 m1 = *(const float4*)&Ush[8192 + i * 128 + q0 + 4];
    const float ur[8] = {r0.x, r0.y, r0.z, r0.w, r1.x, r1.y, r1.z, r1.w};
    const float ui[8] = {m0.x, m0.y, m0.z, m0.w, m1.x, m1.y, m1.z, m1.w};
    const float wa[4] = {wv.x, wv.y, wv.z, wv.w};
#pragma unroll
    for (int a = 0; a < 4; ++a)
#pragma unroll
      for (int k = 0; k < 8; ++k) {
        ar[a][k] = fmaf(wa[a], ur[k], ar[a][k]);
        ai[a][k] = fmaf(wa[a], ui[k], ai[a][k]);
      }
  }
  if (q0 < nb) {   // last tile: nb=8 -> only q0==0 threads write, all 8 valid
#pragma unroll
    for (int a = 0; a < 4; ++a) {
      float* pr = U + (size_t)((2 * f) * 64 + o0 + a) * BNT + bn0 + q0;
      float* pi = U + (size_t)((2 * f + 1) * 64 + o0 + a) * BNT + bn0 + q0;
      *(float4*)pr       = make_float4(ar[a][0], ar[a][1], ar[a][2], ar[a][3]);
      *(float4*)(pr + 4) = make_float4(ar[a][4], ar[a][5], ar[a][6], ar[a][7]);
      *(float4*)pi       = make_float4(ai[a][0], ai[a][1], ai[a][2], ai[a][3]);
      *(float4*)(pi + 4) = make_float4(ai[a][4], ai[a][5], ai[a][6], ai[a][7]);
    }
  }
}

// ---------------------------------------------------------------------------
// K3: ISTFT + OLA + env division.  WG per (b, o, 64-output-frame tile):
// loads Y[cf][o][n0..n0+64] (65 frames), iDFT GEMM -> C'[fl][j] = w[j]*s_fl[j]
// in LDS, then each output sample p = 32(n0+1)+q combines its exactly-2
// covering frames; env = 0.5*(1+cos^2) in closed form.  513 = 8*64+1 exactly.
// ---------------------------------------------------------------------------
__global__ __launch_bounds__(256) void k3_istft(const float* __restrict__ Y,
                                                float* __restrict__ out) {
  const int tile = blockIdx.x;   // 0..7
  const int o    = blockIdx.y;
  const int b    = blockIdx.z;
  const int n0 = tile * 64;
  const int tid = threadIdx.x;
  __shared__ float Ysh[66 * 66];   // [cf][fl], 65 used, stride 66
  __shared__ float Bt[66 * 64];    // [cf][j]  iDFT * window
  __shared__ float Csh[65 * 68];   // [fl][j], stride 68 (16B-aligned rows)

  for (int idx = tid; idx < 66 * 65; idx += 256) {
    const int cf = idx / 65;
    const int fl = idx - cf * 65;
    Ysh[cf * 66 + fl] = Y[(size_t)(cf * 64 + o) * BNT + b * NFRAMES + n0 + fl];
  }
  for (int idx = tid; idx < 66 * 64; idx += 256) {
    const int cf = idx >> 6, j = idx & 63;
    const int f = cf >> 1;
    const float ang = (float)((f * j) & 63) * PI32;
    const float wj = 0.5f * (1.0f - cosf((float)j * PI32));
    const float sc = ((f == 0) || (f == 32)) ? 0.015625f : 0.03125f;  // 1/64, 2/64
    Bt[idx] = ((cf & 1) ? -sc * sinf(ang) : sc * cosf(ang)) * wj;
  }
  __syncthreads();

  // thread tile: 2 frames x 8 j  (covers fl 0..63; fl=64 in epilogue)
  const int fl0 = 2 * (tid >> 3);
  const int j0 = 8 * (tid & 7);
  float a0[8], a1[8];
#pragma unroll
  for (int k = 0; k < 8; ++k) { a0[k] = 0.f; a1[k] = 0.f; }
#pragma unroll 6
  for (int cf = 0; cf < 66; ++cf) {
    const float2 av = *(const float2*)&Ysh[cf * 66 + fl0];
    const float4 b0 = *(const float4*)&Bt[cf * 64 + j0];
    const float4 b1 = *(const float4*)&Bt[cf * 64 + j0 + 4];
    const float bv[8] = {b0.x, b0.y, b0.z, b0.w, b1.x, b1.y, b1.z, b1.w};
#pragma unroll
    for (int k = 0; k < 8; ++k) {
      a0[k] = fmaf(av.x, bv[k], a0[k]);
      a1[k] = fmaf(av.y, bv[k], a1[k]);
    }
  }
  *(float4*)&Csh[fl0 * 68 + j0]           = make_float4(a0[0], a0[1], a0[2], a0[3]);
  *(float4*)&Csh[fl0 * 68 + j0 + 4]       = make_float4(a0[4], a0[5], a0[6], a0[7]);
  *(float4*)&Csh[(fl0 + 1) * 68 + j0]     = make_float4(a1[0], a1[1], a1[2], a1[3]);
  *(float4*)&Csh[(fl0 + 1) * 68 + j0 + 4] = make_float4(a1[4], a1[5], a1[6], a1[7]);
  if (tid < 32) {   // fl = 64 row, only j<32 is ever read
    float s = 0.f;
#pragma unroll 6
    for (int cf = 0; cf < 66; ++cf)
      s = fmaf(Ysh[cf * 66 + 64], Bt[cf * 64 + tid], s);
    Csh[64 * 68 + tid] = s;
  }
  __syncthreads();

  // output: t = 32*n0 + q, q in [0,2048); p = t+32; frames fl2 = 1+(q>>5), fl2-1
  const int q0 = 8 * tid;
  const int j2 = q0 & 31;
  const int fl2 = 1 + (q0 >> 5);
  const float4 lo0 = *(const float4*)&Csh[fl2 * 68 + j2];
  const float4 lo1 = *(const float4*)&Csh[fl2 * 68 + j2 + 4];
  const float4 hi0 = *(const float4*)&Csh[(fl2 - 1) * 68 + j2 + 32];
  const float4 hi1 = *(const float4*)&Csh[(fl2 - 1) * 68 + j2 + 36];
  float v[8] = {lo0.x + hi0.x, lo0.y + hi0.y, lo0.z + hi0.z, lo0.w + hi0.w,
                lo1.x + hi1.x, lo1.y + hi1.y, lo1.z + hi1.z, lo1.w + hi1.w};
#pragma unroll
  for (int k = 0; k < 8; ++k) {
    const float c = cosf((float)(j2 + k) * PI32);
    v[k] = v[k] / (0.5f * (1.0f + c * c));   // env = w[m]^2 + w[m+32]^2
  }
  float* po = out + (size_t)(b * 64 + o) * TT + 32 * n0 + q0;
  *(float4*)po       = make_float4(v[0], v[1], v[2], v[3]);
  *(float4*)(po + 4) = make_float4(v[4], v[5], v[6], v[7]);
}

// ---------------------------------------------------------------------------
extern "C" void kernel_launch(void* const* d_in, const int* in_sizes, int n_in,
                              void* d_out, int out_size, void* d_ws, size_t ws_size,
                              hipStream_t stream) {
  const float* x  = (const float*)d_in[0];   // [8,64,16384]
  const float* wt = (const float*)d_in[1];   // [64,64,33]
  float* out = (float*)d_out;                // [8,64,16384]
  float* U = (float*)d_ws;                   // 66*64*4104 floats = 69.3 MB

  dim3 blk(256);
  k1_stft <<<dim3(9, 64, 8),  blk, 0, stream>>>(x, U);
  k2_mix  <<<dim3(33, 33, 1), blk, 0, stream>>>(wt, U);
  k3_istft<<<dim3(8, 64, 8),  blk, 0, stream>>>(U, out);
}

// Round 2
// 297.167 us; speedup vs baseline: 1.0932x; 1.0932x over previous
//
#include <hip/hip_runtime.h>
#include <cstddef>

#define TT 16384
#define NFRAMES 513
#define BNT 4104              // 8 * 513
#define PI32 0.09817477042468103870f   // pi/32

// ---------------------------------------------------------------------------
// K1: STFT.  x[b][ch][t] -> U[fc][ch][bn],  fc = 2f+c (re/im interleaved rows),
// bn = b*513 + n.  Trig via 64-entry LDS table (all angles are multiples of
// pi/32; sin(t) = cos(t+48 mod 64)).  Register-tiled 64x64x64 GEMM, thread
// tile 4 fc x 4 fl (2x ds_read_b128 per k-step).  f=32 epilogue (imag = 0).
// ---------------------------------------------------------------------------
__global__ __launch_bounds__(256) void k1_stft(const float* __restrict__ x,
                                               float* __restrict__ U) {
  const int tile = blockIdx.x;   // 0..8  (frame tiles of 64; last has 1 frame)
  const int ch   = blockIdx.y;   // input channel
  const int b    = blockIdx.z;
  const int F0 = tile * 64;
  const int nf = min(64, NFRAMES - F0);
  const int tid = threadIdx.x;

  __shared__ float trig[64];         // cos(t*pi/32)
  __shared__ float xseg[2080];       // padded-signal segment
  __shared__ float Aw[64 * 68];      // [j][fl] windowed frames (stride 68: 16B align)
  __shared__ float Bm[64 * 64];      // [j][fc] DFT matrix, fc<64 (f<32)

  if (tid < 64) trig[tid] = cosf((float)tid * PI32);
  const float* xb = x + (size_t)(b * 64 + ch) * TT;
  const int nseg = 32 * nf + 32;
  for (int s = tid; s < nseg; s += 256) {
    int t = 32 * F0 + s - 32;        // reflect padding (PAD=32)
    if (t < 0) t = -t;
    if (t >= TT) t = 2 * TT - 2 - t;
    xseg[s] = xb[t];
  }
  __syncthreads();
  for (int idx = tid; idx < 64 * 64; idx += 256) {
    const int j = idx >> 6, fc = idx & 63;
    const int f = fc >> 1;
    const int t = (f * j) & 63;
    Bm[idx] = (fc & 1) ? -trig[(t + 48) & 63] : trig[t];   // e^{-i2pi f j/64}
  }
  for (int idx = tid; idx < 64 * 64; idx += 256) {
    const int j = idx >> 6, fl = idx & 63;
    const float wj = 0.5f * (1.0f - trig[j]);              // periodic Hann
    Aw[j * 68 + fl] = (fl < nf) ? wj * xseg[32 * fl + j] : 0.0f;
  }
  __syncthreads();

  // thread tile: 4 fc x 4 fl
  const int fc0 = 4 * (tid >> 4);
  const int fl0 = 4 * (tid & 15);
  float acc[4][4];
#pragma unroll
  for (int c = 0; c < 4; ++c)
#pragma unroll
    for (int e = 0; e < 4; ++e) acc[c][e] = 0.f;
#pragma unroll 8
  for (int j = 0; j < 64; ++j) {
    const float4 av = *(const float4*)&Aw[j * 68 + fl0];
    const float4 bv = *(const float4*)&Bm[j * 64 + fc0];
    const float a4[4] = {av.x, av.y, av.z, av.w};
    const float b4[4] = {bv.x, bv.y, bv.z, bv.w};
#pragma unroll
    for (int c = 0; c < 4; ++c)
#pragma unroll
      for (int e = 0; e < 4; ++e) acc[c][e] = fmaf(b4[c], a4[e], acc[c][e]);
  }
  const int bnb = b * NFRAMES + F0;
  if (fl0 < nf) {
    const int lim = min(4, nf - fl0);   // 4 except last tile (nf==1)
#pragma unroll
    for (int c = 0; c < 4; ++c) {
      float* p = U + (size_t)((fc0 + c) * 64 + ch) * BNT + bnb + fl0;
      for (int e = 0; e < lim; ++e) p[e] = acc[c][e];
    }
  }
  // epilogue: f=32 -> real = sum_j (-1)^j * Aw[j], imag = 0 exactly
  if (tid < nf) {
    const int fl = tid;
    float s = 0.f;
#pragma unroll 8
    for (int j = 0; j < 64; ++j) {
      const float v = Aw[j * 68 + fl];
      s = (j & 1) ? (s - v) : (s + v);
    }
    U[(size_t)(64 * 64 + ch) * BNT + bnb + fl] = s;
    U[(size_t)(65 * 64 + ch) * BNT + bnb + fl] = 0.f;
  }
}

// ---------------------------------------------------------------------------
// K2: channel mix, IN PLACE over U.  For each f (33) and bn-tile (128):
//   Y[2f+c][o][bn] = sum_i W[o][i][f] * U[2f+c][i][bn]
// WG loads its exclusive (rows 2f,2f+1) x (bn tile) region to LDS, computes,
// writes back to the same global region (no cross-WG overlap).
// ---------------------------------------------------------------------------
__global__ __launch_bounds__(256) void k2_mix(const float* __restrict__ Wt,
                                              float* __restrict__ U) {
  const int f   = blockIdx.y;         // 0..32
  const int bn0 = blockIdx.x * 128;   // 33 tiles; last has 8 valid
  const int nb  = min(128, BNT - bn0);
  const int tid = threadIdx.x;
  __shared__ float Ush[2 * 64 * 128];   // [c][i][q]  64 KB
  __shared__ float Wl[64 * 64];         // [i][o]     16 KB

  for (int idx = tid; idx < 2 * 64 * 128; idx += 256) {
    const int c = idx >> 13, i = (idx >> 7) & 63, q = idx & 127;
    Ush[idx] = (q < nb) ? U[(size_t)((2 * f + c) * 64 + i) * BNT + bn0 + q] : 0.f;
  }
  for (int idx = tid; idx < 64 * 64; idx += 256) {
    const int i = idx >> 6, o = idx & 63;
    Wl[idx] = Wt[(size_t)(o * 64 + i) * 33 + f];
  }
  __syncthreads();

  // thread tile: 4 o x 8 bn x {re,im}
  const int o0 = 4 * (tid >> 4);
  const int q0 = 8 * (tid & 15);
  float ar[4][8], ai[4][8];
#pragma unroll
  for (int a = 0; a < 4; ++a)
#pragma unroll
    for (int k = 0; k < 8; ++k) { ar[a][k] = 0.f; ai[a][k] = 0.f; }

#pragma unroll 8
  for (int i = 0; i < 64; ++i) {
    const float4 wv = *(const float4*)&Wl[i * 64 + o0];
    const float4 r0 = *(const float4*)&Ush[i * 128 + q0];
    const float4 r1 = *(const float4*)&Ush[i * 128 + q0 + 4];
    const float4 m0 = *(const float4*)&Ush[8192 + i * 128 + q0];
    const float4 m1 = *(const float4*)&Ush[8192 + i * 128 + q0 + 4];
    const float ur[8] = {r0.x, r0.y, r0.z, r0.w, r1.x, r1.y, r1.z, r1.w};
    const float ui[8] = {m0.x, m0.y, m0.z, m0.w, m1.x, m1.y, m1.z, m1.w};
    const float wa[4] = {wv.x, wv.y, wv.z, wv.w};
#pragma unroll
    for (int a = 0; a < 4; ++a)
#pragma unroll
      for (int k = 0; k < 8; ++k) {
        ar[a][k] = fmaf(wa[a], ur[k], ar[a][k]);
        ai[a][k] = fmaf(wa[a], ui[k], ai[a][k]);
      }
  }
  if (q0 < nb) {   // last tile: nb=8 -> only q0==0 threads write, all 8 valid
#pragma unroll
    for (int a = 0; a < 4; ++a) {
      float* pr = U + (size_t)((2 * f) * 64 + o0 + a) * BNT + bn0 + q0;
      float* pi = U + (size_t)((2 * f + 1) * 64 + o0 + a) * BNT + bn0 + q0;
      *(float4*)pr       = make_float4(ar[a][0], ar[a][1], ar[a][2], ar[a][3]);
      *(float4*)(pr + 4) = make_float4(ar[a][4], ar[a][5], ar[a][6], ar[a][7]);
      *(float4*)pi       = make_float4(ai[a][0], ai[a][1], ai[a][2], ai[a][3]);
      *(float4*)(pi + 4) = make_float4(ai[a][4], ai[a][5], ai[a][6], ai[a][7]);
    }
  }
}

// ---------------------------------------------------------------------------
// K3: ISTFT + OLA + env division.  WG per (b, o, 64-output-frame tile):
// loads Y[cf][o][n0..n0+64] (65 frames), iDFT GEMM -> C'[fl][j] = w[j]*s_fl[j]
// in LDS, then each output sample p = 32(n0+1)+q combines its exactly-2
// covering frames; env = 0.5*(1+cos^2) via precomputed 1/env table.
// Trig via the same 64-entry table trick.  513 = 8*64+1 exactly.
// ---------------------------------------------------------------------------
__global__ __launch_bounds__(256) void k3_istft(const float* __restrict__ Y,
                                                float* __restrict__ out) {
  const int tile = blockIdx.x;   // 0..7
  const int o    = blockIdx.y;
  const int b    = blockIdx.z;
  const int n0 = tile * 64;
  const int tid = threadIdx.x;
  __shared__ float trig[64];
  __shared__ float einv[32];
  __shared__ float Ysh[66 * 66];   // [cf][fl], 65 used, stride 66
  __shared__ float Bt[66 * 64];    // [cf][j]  iDFT * window
  __shared__ float Csh[65 * 68];   // [fl][j], stride 68 (16B-aligned rows)

  if (tid < 64) trig[tid] = cosf((float)tid * PI32);
  for (int idx = tid; idx < 66 * 65; idx += 256) {
    const int cf = idx / 65;
    const int fl = idx - cf * 65;
    Ysh[cf * 66 + fl] = Y[(size_t)(cf * 64 + o) * BNT + b * NFRAMES + n0 + fl];
  }
  __syncthreads();
  for (int idx = tid; idx < 66 * 64; idx += 256) {
    const int cf = idx >> 6, j = idx & 63;
    const int f = cf >> 1;
    const int t = (f * j) & 63;
    const float wj = 0.5f * (1.0f - trig[j]);
    const float sc = ((f == 0) || (f == 32)) ? 0.015625f : 0.03125f;  // 1/64, 2/64
    Bt[idx] = ((cf & 1) ? -sc * trig[(t + 48) & 63] : sc * trig[t]) * wj;
  }
  if (tid < 32) {
    const float c = trig[tid];
    einv[tid] = 2.0f / (1.0f + c * c);   // 1 / (w[m]^2 + w[m+32]^2)
  }
  __syncthreads();

  // thread tile: 2 frames x 8 j  (covers fl 0..63; fl=64 in epilogue)
  const int fl0 = 2 * (tid >> 3);
  const int j0 = 8 * (tid & 7);
  float a0[8], a1[8];
#pragma unroll
  for (int k = 0; k < 8; ++k) { a0[k] = 0.f; a1[k] = 0.f; }
#pragma unroll 6
  for (int cf = 0; cf < 66; ++cf) {
    const float2 av = *(const float2*)&Ysh[cf * 66 + fl0];
    const float4 b0 = *(const float4*)&Bt[cf * 64 + j0];
    const float4 b1 = *(const float4*)&Bt[cf * 64 + j0 + 4];
    const float bv[8] = {b0.x, b0.y, b0.z, b0.w, b1.x, b1.y, b1.z, b1.w};
#pragma unroll
    for (int k = 0; k < 8; ++k) {
      a0[k] = fmaf(av.x, bv[k], a0[k]);
      a1[k] = fmaf(av.y, bv[k], a1[k]);
    }
  }
  *(float4*)&Csh[fl0 * 68 + j0]           = make_float4(a0[0], a0[1], a0[2], a0[3]);
  *(float4*)&Csh[fl0 * 68 + j0 + 4]       = make_float4(a0[4], a0[5], a0[6], a0[7]);
  *(float4*)&Csh[(fl0 + 1) * 68 + j0]     = make_float4(a1[0], a1[1], a1[2], a1[3]);
  *(float4*)&Csh[(fl0 + 1) * 68 + j0 + 4] = make_float4(a1[4], a1[5], a1[6], a1[7]);
  if (tid < 32) {   // fl = 64 row, only j<32 is ever read
    float s = 0.f;
#pragma unroll 6
    for (int cf = 0; cf < 66; ++cf)
      s = fmaf(Ysh[cf * 66 + 64], Bt[cf * 64 + tid], s);
    Csh[64 * 68 + tid] = s;
  }
  __syncthreads();

  // output: t = 32*n0 + q, q in [0,2048); p = t+32; frames fl2 = 1+(q>>5), fl2-1
  const int q0 = 8 * tid;
  const int j2 = q0 & 31;
  const int fl2 = 1 + (q0 >> 5);
  const float4 lo0 = *(const float4*)&Csh[fl2 * 68 + j2];
  const float4 lo1 = *(const float4*)&Csh[fl2 * 68 + j2 + 4];
  const float4 hi0 = *(const float4*)&Csh[(fl2 - 1) * 68 + j2 + 32];
  const float4 hi1 = *(const float4*)&Csh[(fl2 - 1) * 68 + j2 + 36];
  float v[8] = {lo0.x + hi0.x, lo0.y + hi0.y, lo0.z + hi0.z, lo0.w + hi0.w,
                lo1.x + hi1.x, lo1.y + hi1.y, lo1.z + hi1.z, lo1.w + hi1.w};
#pragma unroll
  for (int k = 0; k < 8; ++k) v[k] *= einv[j2 + k];
  float* po = out + (size_t)(b * 64 + o) * TT + 32 * n0 + q0;
  *(float4*)po       = make_float4(v[0], v[1], v[2], v[3]);
  *(float4*)(po + 4) = make_float4(v[4], v[5], v[6], v[7]);
}

// ---------------------------------------------------------------------------
extern "C" void kernel_launch(void* const* d_in, const int* in_sizes, int n_in,
                              void* d_out, int out_size, void* d_ws, size_t ws_size,
                              hipStream_t stream) {
  const float* x  = (const float*)d_in[0];   // [8,64,16384]
  const float* wt = (const float*)d_in[1];   // [64,64,33]
  float* out = (float*)d_out;                // [8,64,16384]
  float* U = (float*)d_ws;                   // 66*64*4104 floats = 69.3 MB

  dim3 blk(256);
  k1_stft <<<dim3(9, 64, 8),  blk, 0, stream>>>(x, U);
  k2_mix  <<<dim3(33, 33, 1), blk, 0, stream>>>(wt, U);
  k3_istft<<<dim3(8, 64, 8),  blk, 0, stream>>>(U, out);
}

// Round 3
// 236.994 us; speedup vs baseline: 1.3708x; 1.2539x over previous
//
#include <hip/hip_runtime.h>
#include <cstddef>

#define TT 16384
#define NFRAMES 513
#define NFP 520                 // frames per batch, padded for 16B alignment
#define BNP (8 * NFP)           // 4160 = 65 * 64 (exact 64-wide tiling)
#define PI32 0.09817477042468103870f   // pi/32

typedef unsigned int u32;
typedef unsigned short u16;

__device__ __forceinline__ float b2f(u16 h) {
  union { u32 u; float f; } v; v.u = ((u32)h) << 16; return v.f;
}
__device__ __forceinline__ u16 f2b(float f) {
  union { float f; u32 u; } v; v.f = f;
  const u32 r = v.u + 0x7FFFu + ((v.u >> 16) & 1u);   // RNE
  return (u16)(r >> 16);
}
__device__ __forceinline__ u32 pack2(float a, float b) {
  return (u32)f2b(a) | ((u32)f2b(b) << 16);
}
__device__ __forceinline__ float2 b2x2(u32 u) {
  union { u32 u; float f; } lo, hi;
  lo.u = u << 16; hi.u = u & 0xFFFF0000u;
  return make_float2(lo.f, hi.f);
}

// ---------------------------------------------------------------------------
// K0: W[o][i][f] -> Wt2[f][i][o] (coalesced per-f slices for K2).
// Wt2 lives in d_out scratch; K3 fully overwrites d_out later.
// ---------------------------------------------------------------------------
__global__ __launch_bounds__(256) void k0_wtrans(const float* __restrict__ Wt,
                                                 float* __restrict__ Wt2) {
  const int f = blockIdx.x;   // 0..32
  for (int idx = threadIdx.x; idx < 64 * 64; idx += 256) {
    const int i = idx >> 6, o = idx & 63;
    Wt2[f * 4096 + idx] = Wt[(size_t)(o * 64 + i) * 33 + f];
  }
}

// ---------------------------------------------------------------------------
// K1: STFT.  x[b][ch][t] -> U[fc][ch][b*520+n] (bf16), fc = 2f+c.
// Trig via 64-entry table; 64x64x64 fp32 register GEMM; f=32 epilogue.
// ---------------------------------------------------------------------------
__global__ __launch_bounds__(256) void k1_stft(const float* __restrict__ x,
                                               u16* __restrict__ U) {
  const int tile = blockIdx.x;   // 0..8
  const int ch   = blockIdx.y;
  const int b    = blockIdx.z;
  const int F0 = tile * 64;
  const int nf = min(64, NFRAMES - F0);
  const int tid = threadIdx.x;

  __shared__ float trig[64];
  __shared__ float xseg[2080];
  __shared__ float Aw[64 * 68];      // [j][fl]
  __shared__ float Bm[64 * 64];      // [j][fc]

  if (tid < 64) trig[tid] = cosf((float)tid * PI32);
  const float* xb = x + (size_t)(b * 64 + ch) * TT;
  if (tile > 0 && tile < 8) {        // interior: no reflection, vector loads
    const float* src = xb + 32 * F0 - 32;
    for (int k = tid; k < 520; k += 256)
      *(float4*)&xseg[4 * k] = *(const float4*)(src + 4 * k);
  } else {
    const int nseg = 32 * nf + 32;
    for (int s = tid; s < nseg; s += 256) {
      int t = 32 * F0 + s - 32;
      if (t < 0) t = -t;
      if (t >= TT) t = 2 * TT - 2 - t;
      xseg[s] = xb[t];
    }
  }
  __syncthreads();
  for (int idx = tid; idx < 64 * 64; idx += 256) {
    const int j = idx >> 6, fc = idx & 63;
    const int f = fc >> 1;
    const int t = (f * j) & 63;
    Bm[idx] = (fc & 1) ? -trig[(t + 48) & 63] : trig[t];
  }
  for (int idx = tid; idx < 64 * 64; idx += 256) {
    const int j = idx >> 6, fl = idx & 63;
    const float wj = 0.5f * (1.0f - trig[j]);
    Aw[j * 68 + fl] = (fl < nf) ? wj * xseg[32 * fl + j] : 0.0f;
  }
  __syncthreads();

  const int fc0 = 4 * (tid >> 4);
  const int fl0 = 4 * (tid & 15);
  float acc[4][4];
#pragma unroll
  for (int c = 0; c < 4; ++c)
#pragma unroll
    for (int e = 0; e < 4; ++e) acc[c][e] = 0.f;
#pragma unroll 8
  for (int j = 0; j < 64; ++j) {
    const float4 av = *(const float4*)&Aw[j * 68 + fl0];
    const float4 bv = *(const float4*)&Bm[j * 64 + fc0];
    const float a4[4] = {av.x, av.y, av.z, av.w};
    const float b4[4] = {bv.x, bv.y, bv.z, bv.w};
#pragma unroll
    for (int c = 0; c < 4; ++c)
#pragma unroll
      for (int e = 0; e < 4; ++e) acc[c][e] = fmaf(b4[c], a4[e], acc[c][e]);
  }
  const int bnb = b * NFP + F0;
  if (F0 + fl0 + 4 <= NFP) {   // tiles 0..7 always; tile 8: fl0 in {0,4} (pad zeros ok)
#pragma unroll
    for (int c = 0; c < 4; ++c) {
      u16* p = U + (size_t)((fc0 + c) * 64 + ch) * BNP + bnb + fl0;
      *(uint2*)p = make_uint2(pack2(acc[c][0], acc[c][1]), pack2(acc[c][2], acc[c][3]));
    }
  }
  if (tid < nf) {   // f=32: real = sum (-1)^j Aw, imag = 0
    const int fl = tid;
    float s = 0.f;
#pragma unroll 8
    for (int j = 0; j < 64; ++j) {
      const float v = Aw[j * 68 + fl];
      s = (j & 1) ? (s - v) : (s + v);
    }
    U[(size_t)(64 * 64 + ch) * BNP + bnb + fl] = f2b(s);
    U[(size_t)(65 * 64 + ch) * BNP + bnb + fl] = 0;
  }
}

// ---------------------------------------------------------------------------
// K2: channel mix, IN PLACE over U (bf16).  grid (65 bn-tiles, 33 f).
// All-vector staging: Ush 32 KB + Wl 16 KB = 48 KB -> 3 blocks/CU.
// ---------------------------------------------------------------------------
__global__ __launch_bounds__(256) void k2_mix(const float* __restrict__ Wt2,
                                              u16* __restrict__ U) {
  const int f   = blockIdx.y;
  const int bn0 = blockIdx.x * 64;   // 65 tiles exactly cover BNP=4160
  const int tid = threadIdx.x;
  __shared__ float Ush[2 * 64 * 64];   // [(c*64+i)][q]
  __shared__ float Wl[64 * 64];        // [i][o]

  const u16* Ub = U + (size_t)(2 * f) * 64 * BNP + bn0;
#pragma unroll
  for (int k = 0; k < 4; ++k) {
    const int fidx = tid + k * 256;      // 0..1023 uint4 chunks
    const int row = fidx >> 3;           // c*64+i
    const int q = (fidx & 7) * 8;
    const uint4 raw = *(const uint4*)(Ub + (size_t)row * BNP + q);
    const float2 p0 = b2x2(raw.x), p1 = b2x2(raw.y), p2 = b2x2(raw.z), p3 = b2x2(raw.w);
    float* d = &Ush[row * 64 + q];
    *(float4*)d       = make_float4(p0.x, p0.y, p1.x, p1.y);
    *(float4*)(d + 4) = make_float4(p2.x, p2.y, p3.x, p3.y);
  }
  const float* Wf = Wt2 + f * 4096;
#pragma unroll
  for (int k = 0; k < 4; ++k) {
    const int e = (tid + k * 256) * 4;
    *(float4*)&Wl[e] = *(const float4*)(Wf + e);
  }
  __syncthreads();

  const int o0 = 4 * (tid >> 4);
  const int q0 = 4 * (tid & 15);
  float ar[4][4], ai[4][4];
#pragma unroll
  for (int a = 0; a < 4; ++a)
#pragma unroll
    for (int e = 0; e < 4; ++e) { ar[a][e] = 0.f; ai[a][e] = 0.f; }
#pragma unroll 8
  for (int i = 0; i < 64; ++i) {
    const float4 wv = *(const float4*)&Wl[i * 64 + o0];
    const float4 ur = *(const float4*)&Ush[i * 64 + q0];
    const float4 ui = *(const float4*)&Ush[4096 + i * 64 + q0];
    const float w4[4] = {wv.x, wv.y, wv.z, wv.w};
    const float r4[4] = {ur.x, ur.y, ur.z, ur.w};
    const float i4[4] = {ui.x, ui.y, ui.z, ui.w};
#pragma unroll
    for (int a = 0; a < 4; ++a)
#pragma unroll
      for (int e = 0; e < 4; ++e) {
        ar[a][e] = fmaf(w4[a], r4[e], ar[a][e]);
        ai[a][e] = fmaf(w4[a], i4[e], ai[a][e]);
      }
  }
#pragma unroll
  for (int a = 0; a < 4; ++a) {
    u16* pr = U + (size_t)((2 * f) * 64 + o0 + a) * BNP + bn0 + q0;
    u16* pi = U + (size_t)((2 * f + 1) * 64 + o0 + a) * BNP + bn0 + q0;
    *(uint2*)pr = make_uint2(pack2(ar[a][0], ar[a][1]), pack2(ar[a][2], ar[a][3]));
    *(uint2*)pi = make_uint2(pack2(ai[a][0], ai[a][1]), pack2(ai[a][2], ai[a][3]));
  }
}

// ---------------------------------------------------------------------------
// K3: ISTFT + OLA + env.  WG per (b, o, 64-frame tile); Y loads as uint4 bf16.
// ---------------------------------------------------------------------------
__global__ __launch_bounds__(256) void k3_istft(const u16* __restrict__ Y,
                                                float* __restrict__ out) {
  const int tile = blockIdx.x;   // 0..7
  const int o    = blockIdx.y;
  const int b    = blockIdx.z;
  const int n0 = tile * 64;
  const int tid = threadIdx.x;
  __shared__ float trig[64];
  __shared__ float einv[32];
  __shared__ float Ysh[66 * 66];   // [cf][fl], 65 used
  __shared__ float Bt[66 * 64];    // [cf][j]
  __shared__ float Csh[65 * 68];   // [fl][j]

  if (tid < 64) trig[tid] = cosf((float)tid * PI32);
  const size_t ybase = (size_t)b * NFP + n0;
  for (int k = tid; k < 66 * 8; k += 256) {   // 8 uint4 per row (64 elems)
    const int cf = k >> 3, c8 = (k & 7) * 8;
    const uint4 raw = *(const uint4*)(Y + (size_t)(cf * 64 + o) * BNP + ybase + c8);
    const float2 p0 = b2x2(raw.x), p1 = b2x2(raw.y), p2 = b2x2(raw.z), p3 = b2x2(raw.w);
    float* d = &Ysh[cf * 66 + c8];
    d[0] = p0.x; d[1] = p0.y; d[2] = p1.x; d[3] = p1.y;
    d[4] = p2.x; d[5] = p2.y; d[6] = p3.x; d[7] = p3.y;
  }
  if (tid < 66)
    Ysh[tid * 66 + 64] = b2f(Y[(size_t)(tid * 64 + o) * BNP + ybase + 64]);
  __syncthreads();
  for (int idx = tid; idx < 66 * 64; idx += 256) {
    const int cf = idx >> 6, j = idx & 63;
    const int fq = cf >> 1;
    const int t = (fq * j) & 63;
    const float wj = 0.5f * (1.0f - trig[j]);
    const float sc = ((fq == 0) || (fq == 32)) ? 0.015625f : 0.03125f;
    Bt[idx] = ((cf & 1) ? -sc * trig[(t + 48) & 63] : sc * trig[t]) * wj;
  }
  if (tid < 32) {
    const float c = trig[tid];
    einv[tid] = 2.0f / (1.0f + c * c);
  }
  __syncthreads();

  const int fl0 = 2 * (tid >> 3);
  const int j0 = 8 * (tid & 7);
  float a0[8], a1[8];
#pragma unroll
  for (int k = 0; k < 8; ++k) { a0[k] = 0.f; a1[k] = 0.f; }
#pragma unroll 6
  for (int cf = 0; cf < 66; ++cf) {
    const float2 av = *(const float2*)&Ysh[cf * 66 + fl0];
    const float4 b0 = *(const float4*)&Bt[cf * 64 + j0];
    const float4 b1 = *(const float4*)&Bt[cf * 64 + j0 + 4];
    const float bv[8] = {b0.x, b0.y, b0.z, b0.w, b1.x, b1.y, b1.z, b1.w};
#pragma unroll
    for (int k = 0; k < 8; ++k) {
      a0[k] = fmaf(av.x, bv[k], a0[k]);
      a1[k] = fmaf(av.y, bv[k], a1[k]);
    }
  }
  *(float4*)&Csh[fl0 * 68 + j0]           = make_float4(a0[0], a0[1], a0[2], a0[3]);
  *(float4*)&Csh[fl0 * 68 + j0 + 4]       = make_float4(a0[4], a0[5], a0[6], a0[7]);
  *(float4*)&Csh[(fl0 + 1) * 68 + j0]     = make_float4(a1[0], a1[1], a1[2], a1[3]);
  *(float4*)&Csh[(fl0 + 1) * 68 + j0 + 4] = make_float4(a1[4], a1[5], a1[6], a1[7]);
  if (tid < 32) {   // fl = 64 halo row, only j<32 read
    float s = 0.f;
#pragma unroll 6
    for (int cf = 0; cf < 66; ++cf)
      s = fmaf(Ysh[cf * 66 + 64], Bt[cf * 64 + tid], s);
    Csh[64 * 68 + tid] = s;
  }
  __syncthreads();

  const int q0 = 8 * tid;
  const int j2 = q0 & 31;
  const int fl2 = 1 + (q0 >> 5);
  const float4 lo0 = *(const float4*)&Csh[fl2 * 68 + j2];
  const float4 lo1 = *(const float4*)&Csh[fl2 * 68 + j2 + 4];
  const float4 hi0 = *(const float4*)&Csh[(fl2 - 1) * 68 + j2 + 32];
  const float4 hi1 = *(const float4*)&Csh[(fl2 - 1) * 68 + j2 + 36];
  float v[8] = {lo0.x + hi0.x, lo0.y + hi0.y, lo0.z + hi0.z, lo0.w + hi0.w,
                lo1.x + hi1.x, lo1.y + hi1.y, lo1.z + hi1.z, lo1.w + hi1.w};
#pragma unroll
  for (int k = 0; k < 8; ++k) v[k] *= einv[j2 + k];
  float* po = out + (size_t)(b * 64 + o) * TT + 32 * n0 + q0;
  *(float4*)po       = make_float4(v[0], v[1], v[2], v[3]);
  *(float4*)(po + 4) = make_float4(v[4], v[5], v[6], v[7]);
}

// ---------------------------------------------------------------------------
extern "C" void kernel_launch(void* const* d_in, const int* in_sizes, int n_in,
                              void* d_out, int out_size, void* d_ws, size_t ws_size,
                              hipStream_t stream) {
  const float* x  = (const float*)d_in[0];   // [8,64,16384]
  const float* wt = (const float*)d_in[1];   // [64,64,33]
  float* out = (float*)d_out;                // [8,64,16384]
  u16* U = (u16*)d_ws;                       // 66*64*4160 bf16 = 35 MB
  float* Wt2 = (float*)d_out;                // scratch; k3 fully overwrites out

  dim3 blk(256);
  k0_wtrans<<<dim3(33),       blk, 0, stream>>>(wt, Wt2);
  k1_stft  <<<dim3(9, 64, 8), blk, 0, stream>>>(x, U);
  k2_mix   <<<dim3(65, 33),   blk, 0, stream>>>(Wt2, U);
  k3_istft <<<dim3(8, 64, 8), blk, 0, stream>>>(U, out);
}

// Round 4
// 223.392 us; speedup vs baseline: 1.4542x; 1.0609x over previous
//
#include <hip/hip_runtime.h>
#include <cstddef>

#define TT 16384
#define NFRAMES 513
#define NFP 520                 // frames per batch, padded for 16B alignment
#define BNP (8 * NFP)           // 4160 = 65 * 64 (exact 64-wide tiling)
#define PI32 0.09817477042468103870f   // pi/32

// table offsets (floats) inside tab = d_ws + 35,143,680 B (after bf16 U)
#define OFF_WT2  0
#define OFF_BM   135168
#define OFF_BT   139264
#define OFF_WIN  143488
#define OFF_EINV 143552

typedef unsigned int u32;
typedef unsigned short u16;

__device__ __forceinline__ float b2f(u16 h) {
  union { u32 u; float f; } v; v.u = ((u32)h) << 16; return v.f;
}
__device__ __forceinline__ u16 f2b(float f) {
  union { float f; u32 u; } v; v.f = f;
  const u32 r = v.u + 0x7FFFu + ((v.u >> 16) & 1u);   // RNE
  return (u16)(r >> 16);
}
__device__ __forceinline__ u32 pack2(float a, float b) {
  return (u32)f2b(a) | ((u32)f2b(b) << 16);
}
__device__ __forceinline__ float2 b2x2(u32 u) {
  union { u32 u; float f; } lo, hi;
  lo.u = u << 16; hi.u = u & 0xFFFF0000u;
  return make_float2(lo.f, hi.f);
}

// ---------------------------------------------------------------------------
// K0: build all constant tables once.
//  blocks 0..32 : Wt2[f][i][o]   (transposed W, coalesced per-f slices)
//  block  33    : BmG[j][fc] = win[j] * DFT  (window folded in), winG, einvG
//  blocks 34,35 : BtG[cf][j] = win[j]*scale*iDFT
// ---------------------------------------------------------------------------
__global__ __launch_bounds__(256) void k0_tables(const float* __restrict__ W,
                                                 float* __restrict__ tab) {
  const int b = blockIdx.x, tid = threadIdx.x;
  if (b < 33) {
    float* Wt2 = tab + OFF_WT2;
    for (int idx = tid; idx < 4096; idx += 256) {
      const int i = idx >> 6, o = idx & 63;
      Wt2[b * 4096 + idx] = W[(size_t)(o * 64 + i) * 33 + b];
    }
  } else if (b == 33) {
    float* BmG = tab + OFF_BM;
    for (int idx = tid; idx < 4096; idx += 256) {
      const int j = idx >> 6, fc = idx & 63, f = fc >> 1;
      const float wj = 0.5f * (1.0f - cosf((float)j * PI32));
      const float ang = (float)((f * j) & 63) * PI32;
      BmG[idx] = wj * ((fc & 1) ? -sinf(ang) : cosf(ang));
    }
    if (tid < 64) tab[OFF_WIN + tid] = 0.5f * (1.0f - cosf((float)tid * PI32));
    if (tid < 32) {
      const float c = cosf((float)tid * PI32);
      tab[OFF_EINV + tid] = 2.0f / (1.0f + c * c);
    }
  } else {
    float* BtG = tab + OFF_BT;
    const int half = b - 34;
    for (int k = tid; k < 2112; k += 256) {
      const int idx = half * 2112 + k;
      const int cf = idx >> 6, j = idx & 63, f = cf >> 1;
      const float wj = 0.5f * (1.0f - cosf((float)j * PI32));
      const float sc = ((f == 0) || (f == 32)) ? 0.015625f : 0.03125f;
      const float ang = (float)((f * j) & 63) * PI32;
      BtG[idx] = wj * sc * ((cf & 1) ? -sinf(ang) : cosf(ang));
    }
  }
}

// ---------------------------------------------------------------------------
// K1: STFT frames 0..511.  x[b][ch][t] -> U[fc][ch][b*520+n] (bf16).
// xseg stored with swizzle XS(s)=s+(s>>5): the framing read xseg[32*fl+j]
// becomes bank (fl+const)%32 -> conflict-free (was 64-way!).
// Window is folded into Bm.  Only tile 0 needs reflect.
// ---------------------------------------------------------------------------
__global__ __launch_bounds__(256) void k1_stft(const float* __restrict__ x,
                                               const float* __restrict__ tab,
                                               u16* __restrict__ U) {
  const int tile = blockIdx.x;   // 0..7, frames F0..F0+63
  const int ch   = blockIdx.y;
  const int b    = blockIdx.z;
  const int F0 = tile * 64;
  const int tid = threadIdx.x;

  __shared__ float xseg[2144];       // swizzled; max XS(2079)=2143
  __shared__ float Aw[64 * 68];      // [j][fl] raw frames (no window)
  __shared__ float Bm[64 * 64];      // [j][fc] win-folded DFT
  __shared__ float win[64];

  const float* BmG = tab + OFF_BM;
#pragma unroll
  for (int k = 0; k < 4; ++k) {
    const int e = (tid + k * 256) * 4;
    *(float4*)&Bm[e] = *(const float4*)(BmG + e);
  }
  if (tid < 64) win[tid] = tab[OFF_WIN + tid];

  const float* xb = x + (size_t)(b * 64 + ch) * TT;
  if (tile > 0) {                    // interior/right: samples 32*F0-32 .. +2079, all valid
    const float* src = xb + 32 * F0 - 32;
    for (int k = tid; k < 520; k += 256) {
      const float4 v = *(const float4*)(src + 4 * k);
      const int s = 4 * k, off = s + (s >> 5);  // float4 never crosses a 32-boundary
      xseg[off] = v.x; xseg[off + 1] = v.y; xseg[off + 2] = v.z; xseg[off + 3] = v.w;
    }
  } else {
    for (int s = tid; s < 2080; s += 256) {
      int t = s - 32;
      if (t < 0) t = -t;             // left reflect
      xseg[s + (s >> 5)] = xb[t];
    }
  }
  __syncthreads();
  for (int idx = tid; idx < 4096; idx += 256) {
    const int j = idx >> 6, fl = idx & 63;
    const int base = j + (j >> 5);
    Aw[j * 68 + fl] = xseg[33 * fl + base];   // conflict-free
  }
  __syncthreads();

  const int fc0 = 4 * (tid >> 4);
  const int fl0 = 4 * (tid & 15);
  float acc[4][4];
#pragma unroll
  for (int c = 0; c < 4; ++c)
#pragma unroll
    for (int e = 0; e < 4; ++e) acc[c][e] = 0.f;
#pragma unroll 8
  for (int j = 0; j < 64; ++j) {
    const float4 av = *(const float4*)&Aw[j * 68 + fl0];
    const float4 bv = *(const float4*)&Bm[j * 64 + fc0];
    const float a4[4] = {av.x, av.y, av.z, av.w};
    const float b4[4] = {bv.x, bv.y, bv.z, bv.w};
#pragma unroll
    for (int c = 0; c < 4; ++c)
#pragma unroll
      for (int e = 0; e < 4; ++e) acc[c][e] = fmaf(b4[c], a4[e], acc[c][e]);
  }
  const int bnb = b * NFP + F0;
#pragma unroll
  for (int c = 0; c < 4; ++c) {
    u16* p = U + (size_t)((fc0 + c) * 64 + ch) * BNP + bnb + fl0;
    *(uint2*)p = make_uint2(pack2(acc[c][0], acc[c][1]), pack2(acc[c][2], acc[c][3]));
  }
  if (tid < 64) {   // f=32: real = sum (-1)^j win[j]*Aw[j], imag = 0
    const int fl = tid;
    float s = 0.f;
#pragma unroll 8
    for (int j = 0; j < 64; ++j) {
      const float v = win[j] * Aw[j * 68 + fl];
      s = (j & 1) ? (s - v) : (s + v);
    }
    U[(size_t)(64 * 64 + ch) * BNP + bnb + fl] = f2b(s);
    U[(size_t)(65 * 64 + ch) * BNP + bnb + fl] = 0;
  }
}

// ---------------------------------------------------------------------------
// K1b: frame 512 (the 513th) for all (b, ch).  grid (4 ch-groups, 8 b).
// ---------------------------------------------------------------------------
__global__ __launch_bounds__(256) void k1b_last(const float* __restrict__ x,
                                                const float* __restrict__ tab,
                                                u16* __restrict__ U) {
  const int cg = blockIdx.x;   // ch0 = 16*cg
  const int b  = blockIdx.y;
  const int tid = threadIdx.x;
  __shared__ float xe[16 * 65];
  __shared__ float Bm[64 * 64];
  __shared__ float win[64];
  const float* BmG = tab + OFF_BM;
#pragma unroll
  for (int k = 0; k < 4; ++k) {
    const int e = (tid + k * 256) * 4;
    *(float4*)&Bm[e] = *(const float4*)(BmG + e);
  }
  if (tid < 64) win[tid] = tab[OFF_WIN + tid];
  for (int idx = tid; idx < 16 * 64; idx += 256) {
    const int c = idx >> 6, j = idx & 63;
    const int t = (j < 32) ? (16352 + j) : (16414 - j);   // right reflect
    xe[c * 65 + j] = x[(size_t)(b * 64 + 16 * cg + c) * TT + t];
  }
  __syncthreads();
  for (int idx = tid; idx < 66 * 16; idx += 256) {
    const int fc = idx >> 4, c = idx & 15;
    float s = 0.f;
    if (fc < 64) {
#pragma unroll 8
      for (int j = 0; j < 64; ++j) s = fmaf(xe[c * 65 + j], Bm[j * 64 + fc], s);
    } else if (fc == 64) {
#pragma unroll 8
      for (int j = 0; j < 64; ++j) {
        const float v = win[j] * xe[c * 65 + j];
        s = (j & 1) ? (s - v) : (s + v);
      }
    }
    U[(size_t)(fc * 64 + 16 * cg + c) * BNP + b * NFP + 512] = f2b(s);
  }
}

// ---------------------------------------------------------------------------
// K2: channel mix, IN PLACE over U (bf16).  grid (65 bn-tiles, 33 f).
// ---------------------------------------------------------------------------
__global__ __launch_bounds__(256) void k2_mix(const float* __restrict__ tab,
                                              u16* __restrict__ U) {
  const int f   = blockIdx.y;
  const int bn0 = blockIdx.x * 64;
  const int tid = threadIdx.x;
  __shared__ float Ush[2 * 64 * 64];   // [(c*64+i)][q]
  __shared__ float Wl[64 * 64];        // [i][o]

  const u16* Ub = U + (size_t)(2 * f) * 64 * BNP + bn0;
#pragma unroll
  for (int k = 0; k < 4; ++k) {
    const int fidx = tid + k * 256;
    const int row = fidx >> 3;
    const int q = (fidx & 7) * 8;
    const uint4 raw = *(const uint4*)(Ub + (size_t)row * BNP + q);
    const float2 p0 = b2x2(raw.x), p1 = b2x2(raw.y), p2 = b2x2(raw.z), p3 = b2x2(raw.w);
    float* d = &Ush[row * 64 + q];
    *(float4*)d       = make_float4(p0.x, p0.y, p1.x, p1.y);
    *(float4*)(d + 4) = make_float4(p2.x, p2.y, p3.x, p3.y);
  }
  const float* Wf = tab + OFF_WT2 + f * 4096;
#pragma unroll
  for (int k = 0; k < 4; ++k) {
    const int e = (tid + k * 256) * 4;
    *(float4*)&Wl[e] = *(const float4*)(Wf + e);
  }
  __syncthreads();

  const int o0 = 4 * (tid >> 4);
  const int q0 = 4 * (tid & 15);
  float ar[4][4], ai[4][4];
#pragma unroll
  for (int a = 0; a < 4; ++a)
#pragma unroll
    for (int e = 0; e < 4; ++e) { ar[a][e] = 0.f; ai[a][e] = 0.f; }
#pragma unroll 8
  for (int i = 0; i < 64; ++i) {
    const float4 wv = *(const float4*)&Wl[i * 64 + o0];
    const float4 ur = *(const float4*)&Ush[i * 64 + q0];
    const float4 ui = *(const float4*)&Ush[4096 + i * 64 + q0];
    const float w4[4] = {wv.x, wv.y, wv.z, wv.w};
    const float r4[4] = {ur.x, ur.y, ur.z, ur.w};
    const float i4[4] = {ui.x, ui.y, ui.z, ui.w};
#pragma unroll
    for (int a = 0; a < 4; ++a)
#pragma unroll
      for (int e = 0; e < 4; ++e) {
        ar[a][e] = fmaf(w4[a], r4[e], ar[a][e]);
        ai[a][e] = fmaf(w4[a], i4[e], ai[a][e]);
      }
  }
#pragma unroll
  for (int a = 0; a < 4; ++a) {
    u16* pr = U + (size_t)((2 * f) * 64 + o0 + a) * BNP + bn0 + q0;
    u16* pi = U + (size_t)((2 * f + 1) * 64 + o0 + a) * BNP + bn0 + q0;
    *(uint2*)pr = make_uint2(pack2(ar[a][0], ar[a][1]), pack2(ar[a][2], ar[a][3]));
    *(uint2*)pi = make_uint2(pack2(ai[a][0], ai[a][1]), pack2(ai[a][2], ai[a][3]));
  }
}

// ---------------------------------------------------------------------------
// K3: ISTFT + OLA + env.  Bt/einv loaded from global tables (single barrier).
// ---------------------------------------------------------------------------
__global__ __launch_bounds__(256) void k3_istft(const u16* __restrict__ Y,
                                                const float* __restrict__ tab,
                                                float* __restrict__ out) {
  const int tile = blockIdx.x;   // 0..7
  const int o    = blockIdx.y;
  const int b    = blockIdx.z;
  const int n0 = tile * 64;
  const int tid = threadIdx.x;
  __shared__ float einv[32];
  __shared__ float Ysh[66 * 66];   // [cf][fl], 65 used
  __shared__ float Bt[66 * 64];    // [cf][j]
  __shared__ float Csh[65 * 68];   // [fl][j]

  const size_t ybase = (size_t)b * NFP + n0;
  for (int k = tid; k < 66 * 8; k += 256) {
    const int cf = k >> 3, c8 = (k & 7) * 8;
    const uint4 raw = *(const uint4*)(Y + (size_t)(cf * 64 + o) * BNP + ybase + c8);
    const float2 p0 = b2x2(raw.x), p1 = b2x2(raw.y), p2 = b2x2(raw.z), p3 = b2x2(raw.w);
    float* d = &Ysh[cf * 66 + c8];
    d[0] = p0.x; d[1] = p0.y; d[2] = p1.x; d[3] = p1.y;
    d[4] = p2.x; d[5] = p2.y; d[6] = p3.x; d[7] = p3.y;
  }
  if (tid < 66)
    Ysh[tid * 66 + 64] = b2f(Y[(size_t)(tid * 64 + o) * BNP + ybase + 64]);
  const float* BtG = tab + OFF_BT;
  for (int k = tid; k < 1056; k += 256)
    *(float4*)&Bt[4 * k] = *(const float4*)(BtG + 4 * k);
  if (tid < 32) einv[tid] = tab[OFF_EINV + tid];
  __syncthreads();

  const int fl0 = 2 * (tid >> 3);
  const int j0 = 8 * (tid & 7);
  float a0[8], a1[8];
#pragma unroll
  for (int k = 0; k < 8; ++k) { a0[k] = 0.f; a1[k] = 0.f; }
#pragma unroll 6
  for (int cf = 0; cf < 66; ++cf) {
    const float2 av = *(const float2*)&Ysh[cf * 66 + fl0];
    const float4 b0 = *(const float4*)&Bt[cf * 64 + j0];
    const float4 b1 = *(const float4*)&Bt[cf * 64 + j0 + 4];
    const float bv[8] = {b0.x, b0.y, b0.z, b0.w, b1.x, b1.y, b1.z, b1.w};
#pragma unroll
    for (int k = 0; k < 8; ++k) {
      a0[k] = fmaf(av.x, bv[k], a0[k]);
      a1[k] = fmaf(av.y, bv[k], a1[k]);
    }
  }
  *(float4*)&Csh[fl0 * 68 + j0]           = make_float4(a0[0], a0[1], a0[2], a0[3]);
  *(float4*)&Csh[fl0 * 68 + j0 + 4]       = make_float4(a0[4], a0[5], a0[6], a0[7]);
  *(float4*)&Csh[(fl0 + 1) * 68 + j0]     = make_float4(a1[0], a1[1], a1[2], a1[3]);
  *(float4*)&Csh[(fl0 + 1) * 68 + j0 + 4] = make_float4(a1[4], a1[5], a1[6], a1[7]);
  if (tid < 32) {   // fl = 64 halo row, only j<32 read
    float s = 0.f;
#pragma unroll 6
    for (int cf = 0; cf < 66; ++cf)
      s = fmaf(Ysh[cf * 66 + 64], Bt[cf * 64 + tid], s);
    Csh[64 * 68 + tid] = s;
  }
  __syncthreads();

  const int q0 = 8 * tid;
  const int j2 = q0 & 31;
  const int fl2 = 1 + (q0 >> 5);
  const float4 lo0 = *(const float4*)&Csh[fl2 * 68 + j2];
  const float4 lo1 = *(const float4*)&Csh[fl2 * 68 + j2 + 4];
  const float4 hi0 = *(const float4*)&Csh[(fl2 - 1) * 68 + j2 + 32];
  const float4 hi1 = *(const float4*)&Csh[(fl2 - 1) * 68 + j2 + 36];
  float v[8] = {lo0.x + hi0.x, lo0.y + hi0.y, lo0.z + hi0.z, lo0.w + hi0.w,
                lo1.x + hi1.x, lo1.y + hi1.y, lo1.z + hi1.z, lo1.w + hi1.w};
#pragma unroll
  for (int k = 0; k < 8; ++k) v[k] *= einv[j2 + k];
  float* po = out + (size_t)(b * 64 + o) * TT + 32 * n0 + q0;
  *(float4*)po       = make_float4(v[0], v[1], v[2], v[3]);
  *(float4*)(po + 4) = make_float4(v[4], v[5], v[6], v[7]);
}

// ---------------------------------------------------------------------------
extern "C" void kernel_launch(void* const* d_in, const int* in_sizes, int n_in,
                              void* d_out, int out_size, void* d_ws, size_t ws_size,
                              hipStream_t stream) {
  const float* x  = (const float*)d_in[0];   // [8,64,16384]
  const float* wt = (const float*)d_in[1];   // [64,64,33]
  float* out = (float*)d_out;                // [8,64,16384]
  u16* U = (u16*)d_ws;                       // 66*64*4160 bf16 = 35.1 MB
  float* tab = (float*)((char*)d_ws + (size_t)66 * 64 * BNP * 2);  // tables, 574 KB

  dim3 blk(256);
  k0_tables<<<dim3(36),       blk, 0, stream>>>(wt, tab);
  k1_stft  <<<dim3(8, 64, 8), blk, 0, stream>>>(x, tab, U);
  k1b_last <<<dim3(4, 8),     blk, 0, stream>>>(x, tab, U);
  k2_mix   <<<dim3(65, 33),   blk, 0, stream>>>(tab, U);
  k3_istft <<<dim3(8, 64, 8), blk, 0, stream>>>(U, tab, out);
}

// Round 5
// 172.629 us; speedup vs baseline: 1.8819x; 1.2941x over previous
//
#include <hip/hip_runtime.h>
#include <cstddef>

#define TT 16384
#define NFRAMES 513
#define NFP 520                 // frames per batch, padded
#define BNP (8 * NFP)           // 4160 = 65 * 64
#define PI32 0.09817477042468103870f   // pi/32

typedef unsigned int u32;
typedef unsigned short u16;
typedef __attribute__((ext_vector_type(8))) short bf16x8;
typedef __attribute__((ext_vector_type(4))) float f32x4;

// u16-table layout after U (35,143,680 B): Wbf[33][64][72], Bm[80][72]
#define TAB_WBF 0
#define TAB_BM  (33 * 64 * 72)
#define TAB_TOT (TAB_BM + 80 * 72)      // 157824 u16 = 315648 B (16B-aligned)
// f32 tables after that
#define TF_BT   0                       // 66*64
#define TF_EINV 4224                    // 32

__device__ __forceinline__ float b2f(u16 h) {
  union { u32 u; float f; } v; v.u = ((u32)h) << 16; return v.f;
}
__device__ __forceinline__ u16 f2b(float f) {
  union { float f; u32 u; } v; v.f = f;
  const u32 r = v.u + 0x7FFFu + ((v.u >> 16) & 1u);   // RNE
  return (u16)(r >> 16);
}
__device__ __forceinline__ u32 pack2(float a, float b) {
  return (u32)f2b(a) | ((u32)f2b(b) << 16);
}
__device__ __forceinline__ float2 b2x2(u32 u) {
  union { u32 u; float f; } lo, hi;
  lo.u = u << 16; hi.u = u & 0xFFFF0000u;
  return make_float2(lo.f, hi.f);
}

// ---------------------------------------------------------------------------
// K0: constant tables.
//  blocks 0..32: Wbf[f][o][i] bf16 (stride 72, A-operand-ready)
//  block 33    : Bm[fc 0..79][j 0..71] bf16: rows 0..63 win*DFT, row 64
//                (-1)^j*win (f=32 real), rows 65..79 zero
//  blocks 34/35: Bt fp32 iDFT table + einv
// ---------------------------------------------------------------------------
__global__ __launch_bounds__(256) void k0_tables(const float* __restrict__ W,
                                                 u16* __restrict__ t16,
                                                 float* __restrict__ tf) {
  const int b = blockIdx.x, tid = threadIdx.x;
  if (b < 33) {
    for (int idx = tid; idx < 64 * 72; idx += 256) {
      const int o = idx / 72, i = idx % 72;
      const float v = (i < 64) ? W[(size_t)(o * 64 + i) * 33 + b] : 0.f;
      t16[TAB_WBF + b * 64 * 72 + idx] = f2b(v);
    }
  } else if (b == 33) {
    for (int idx = tid; idx < 80 * 72; idx += 256) {
      const int fc = idx / 72, j = idx % 72;
      float v = 0.f;
      if (j < 64 && fc < 65) {
        const float wj = 0.5f * (1.0f - cosf((float)j * PI32));
        if (fc < 64) {
          const int f = fc >> 1;
          const float ang = (float)((f * j) & 63) * PI32;
          v = wj * ((fc & 1) ? -sinf(ang) : cosf(ang));
        } else {
          v = (j & 1) ? -wj : wj;   // f=32 real row
        }
      }
      t16[TAB_BM + idx] = f2b(v);
    }
  } else {
    const int half = b - 34;
    for (int k = tid; k < 2112; k += 256) {
      const int idx = half * 2112 + k;
      const int cf = idx >> 6, j = idx & 63, f = cf >> 1;
      const float wj = 0.5f * (1.0f - cosf((float)j * PI32));
      const float sc = ((f == 0) || (f == 32)) ? 0.015625f : 0.03125f;
      const float ang = (float)((f * j) & 63) * PI32;
      tf[TF_BT + idx] = wj * sc * ((cf & 1) ? -sinf(ang) : cosf(ang));
    }
    if (b == 35 && tid < 32) {
      const float c = cosf((float)tid * PI32);
      tf[TF_EINV + tid] = 2.0f / (1.0f + c * c);
    }
  }
}

// ---------------------------------------------------------------------------
// K1: STFT frames 0..511 via MFMA.  C[fc 0..65][fl 0..63] = Bm(80x64) x
// Awt(64 frames x 64 samples)^T per (tile, ch, b).  Frames built straight
// from float4 x loads (each 4-sample chunk lands in 2 overlapping frames).
// ---------------------------------------------------------------------------
__global__ __launch_bounds__(256) void k1_stft(const float* __restrict__ x,
                                               const u16* __restrict__ t16,
                                               u16* __restrict__ U) {
  const int tile = blockIdx.x;   // 0..7
  const int ch   = blockIdx.y;
  const int b    = blockIdx.z;
  const int F0 = tile * 64;
  const int tid = threadIdx.x;
  __shared__ __align__(16) u16 Bm[80 * 72];
  __shared__ __align__(16) u16 Awt[64 * 72];   // [fl][j] bf16 frames

  for (int k = tid; k < 720; k += 256)
    ((uint4*)Bm)[k] = ((const uint4*)(t16 + TAB_BM))[k];

  const float* xb = x + (size_t)(b * 64 + ch) * TT;
  if (tile == 0) {
    if (tid < 32) Awt[tid] = f2b(xb[32 - tid]);      // left reflect, frame 0
    for (int c = 8 + tid; c < 520; c += 256) {       // s = 4c >= 32 -> t = 4c-32
      const float4 v = *(const float4*)(xb + 4 * c - 32);
      const uint2 pk = make_uint2(pack2(v.x, v.y), pack2(v.z, v.w));
      const int flb = c >> 3, jj = 4 * (c & 7);
      if (flb < 64) *(uint2*)&Awt[flb * 72 + jj] = pk;
      *(uint2*)&Awt[(flb - 1) * 72 + 32 + jj] = pk;  // flb >= 1 here
    }
  } else {
    const float* src = xb + 32 * F0 - 32;
    for (int c = tid; c < 520; c += 256) {
      const float4 v = *(const float4*)(src + 4 * c);
      const uint2 pk = make_uint2(pack2(v.x, v.y), pack2(v.z, v.w));
      const int flb = c >> 3, jj = 4 * (c & 7);
      if (flb < 64) *(uint2*)&Awt[flb * 72 + jj] = pk;
      if (flb >= 1) *(uint2*)&Awt[(flb - 1) * 72 + 32 + jj] = pk;
    }
  }
  __syncthreads();

  const int wave = tid >> 6, lane = tid & 63;
  const int n = lane & 15, quad = lane >> 4;

  bf16x8 bfr[4][2];
#pragma unroll
  for (int nt = 0; nt < 4; ++nt)
#pragma unroll
    for (int ks = 0; ks < 2; ++ks)
      bfr[nt][ks] = *(const bf16x8*)&Awt[(nt * 16 + n) * 72 + ks * 32 + quad * 8];

  const int bnb = b * NFP + F0;
  const int npass = (wave == 0) ? 2 : 1;   // wave 0 also does m-tile 4 (fc 64..65)
  for (int pass = 0; pass < npass; ++pass) {
    const int mt = pass ? 4 : wave;
    bf16x8 af[2];
#pragma unroll
    for (int ks = 0; ks < 2; ++ks)
      af[ks] = *(const bf16x8*)&Bm[(mt * 16 + n) * 72 + ks * 32 + quad * 8];
    f32x4 acc[4];
#pragma unroll
    for (int nt = 0; nt < 4; ++nt) acc[nt] = (f32x4){0.f, 0.f, 0.f, 0.f};
#pragma unroll
    for (int ks = 0; ks < 2; ++ks)
#pragma unroll
      for (int nt = 0; nt < 4; ++nt)
        acc[nt] = __builtin_amdgcn_mfma_f32_16x16x32_bf16(af[ks], bfr[nt][ks],
                                                          acc[nt], 0, 0, 0);
#pragma unroll
    for (int nt = 0; nt < 4; ++nt) {
      const int fl = nt * 16 + n;
#pragma unroll
      for (int r = 0; r < 4; ++r) {
        const int fc = mt * 16 + quad * 4 + r;
        if (fc < 66)
          U[(size_t)(fc * 64 + ch) * BNP + bnb + fl] = f2b(acc[nt][r]);
      }
    }
  }
}

// ---------------------------------------------------------------------------
// K1b: frame 512 for all (b, ch).  Small fp32 dot products, Bm bf16 rows
// (row 64 = signed window, row 65 = zeros -> uniform loop).
// ---------------------------------------------------------------------------
__global__ __launch_bounds__(256) void k1b_last(const float* __restrict__ x,
                                                const u16* __restrict__ t16,
                                                u16* __restrict__ U) {
  const int cg = blockIdx.x;   // ch0 = 16*cg
  const int b  = blockIdx.y;
  const int tid = threadIdx.x;
  __shared__ float xe[16 * 65];
  __shared__ __align__(16) u16 Bsh[80 * 72];
  for (int k = tid; k < 720; k += 256)
    ((uint4*)Bsh)[k] = ((const uint4*)(t16 + TAB_BM))[k];
  for (int idx = tid; idx < 16 * 64; idx += 256) {
    const int c = idx >> 6, j = idx & 63;
    const int t = (j < 32) ? (16352 + j) : (16414 - j);   // right reflect
    xe[c * 65 + j] = x[(size_t)(b * 64 + 16 * cg + c) * TT + t];
  }
  __syncthreads();
  for (int idx = tid; idx < 66 * 16; idx += 256) {
    const int fc = idx >> 4, c = idx & 15;
    float s = 0.f;
#pragma unroll 8
    for (int j = 0; j < 64; ++j)
      s = fmaf(xe[c * 65 + j], b2f(Bsh[fc * 72 + j]), s);
    U[(size_t)(fc * 64 + 16 * cg + c) * BNP + b * NFP + 512] = f2b(s);
  }
}

// ---------------------------------------------------------------------------
// K2: channel mix via MFMA, IN PLACE over U.  Per (f, 64-wide q-tile):
// C[o][q] = W(64x64) x Ut(q x i), both re and im share the W A-fragments.
// Ut is the LDS-transposed U tile with XOR chunk swizzle
// (chunk' = (i>>3) ^ ((q>>3)&7)) -> conflict-free b128 fragment reads.
// ---------------------------------------------------------------------------
__global__ __launch_bounds__(256) void k2_mix(const u16* __restrict__ t16,
                                              u16* __restrict__ U) {
  const int f   = blockIdx.y;
  const int bn0 = blockIdx.x * 64;
  const int tid = threadIdx.x;
  __shared__ __align__(16) u16 Ut[2 * 64 * 72];   // [c][q][i swizzled]
  __shared__ __align__(16) u16 Wl[64 * 72];       // [o][i]

  for (int k = tid; k < 576; k += 256)
    ((uint4*)Wl)[k] = ((const uint4*)(t16 + TAB_WBF + f * 64 * 72))[k];

#pragma unroll
  for (int kk = 0; kk < 4; ++kk) {
    const int id = tid + kk * 256;          // 0..1023 uint4 chunks
    const int c = id >> 9, rem = id & 511;
    const int i = rem >> 3, qc = rem & 7;   // 8 q's per chunk at fixed i
    const uint4 raw = *(const uint4*)(U + (size_t)((2 * f + c) * 64 + i) * BNP + bn0 + 8 * qc);
    const int col = (((i >> 3) ^ qc) << 3) + (i & 7);   // swz(q)=qc for this chunk
    u16* base = &Ut[c * 4608 + col];
#pragma unroll
    for (int e = 0; e < 8; ++e) {
      const u32 w = ((const u32*)&raw)[e >> 1];
      base[(8 * qc + e) * 72] = (u16)((e & 1) ? (w >> 16) : (w & 0xFFFFu));
    }
  }
  __syncthreads();

  const int wave = tid >> 6, lane = tid & 63;
  const int n = lane & 15, quad = lane >> 4;
  const int mt = wave;

  bf16x8 af[2];
#pragma unroll
  for (int ks = 0; ks < 2; ++ks)
    af[ks] = *(const bf16x8*)&Wl[(mt * 16 + n) * 72 + ks * 32 + quad * 8];

  f32x4 acc[4][2];
#pragma unroll
  for (int nt = 0; nt < 4; ++nt)
#pragma unroll
    for (int c = 0; c < 2; ++c) acc[nt][c] = (f32x4){0.f, 0.f, 0.f, 0.f};

#pragma unroll
  for (int ks = 0; ks < 2; ++ks)
#pragma unroll
    for (int nt = 0; nt < 4; ++nt) {
      const int q = nt * 16 + n;
      const int chunk = (((ks << 2) + quad) ^ ((q >> 3) & 7)) << 3;
#pragma unroll
      for (int c = 0; c < 2; ++c) {
        const bf16x8 bf = *(const bf16x8*)&Ut[c * 4608 + q * 72 + chunk];
        acc[nt][c] = __builtin_amdgcn_mfma_f32_16x16x32_bf16(af[ks], bf,
                                                             acc[nt][c], 0, 0, 0);
      }
    }

#pragma unroll
  for (int nt = 0; nt < 4; ++nt) {
    const int q = bn0 + nt * 16 + n;
#pragma unroll
    for (int c = 0; c < 2; ++c)
#pragma unroll
      for (int r = 0; r < 4; ++r) {
        const int o = mt * 16 + quad * 4 + r;
        U[(size_t)((2 * f + c) * 64 + o) * BNP + q] = f2b(acc[nt][c][r]);
      }
  }
}

// ---------------------------------------------------------------------------
// K3: ISTFT + OLA + env (fp32, unchanged structurally).
// ---------------------------------------------------------------------------
__global__ __launch_bounds__(256) void k3_istft(const u16* __restrict__ Y,
                                                const float* __restrict__ tf,
                                                float* __restrict__ out) {
  const int tile = blockIdx.x;   // 0..7
  const int o    = blockIdx.y;
  const int b    = blockIdx.z;
  const int n0 = tile * 64;
  const int tid = threadIdx.x;
  __shared__ float einv[32];
  __shared__ float Ysh[66 * 66];   // [cf][fl], 65 used
  __shared__ float Bt[66 * 64];    // [cf][j]
  __shared__ float Csh[65 * 68];   // [fl][j]

  const size_t ybase = (size_t)b * NFP + n0;
  for (int k = tid; k < 66 * 8; k += 256) {
    const int cf = k >> 3, c8 = (k & 7) * 8;
    const uint4 raw = *(const uint4*)(Y + (size_t)(cf * 64 + o) * BNP + ybase + c8);
    const float2 p0 = b2x2(raw.x), p1 = b2x2(raw.y), p2 = b2x2(raw.z), p3 = b2x2(raw.w);
    float* d = &Ysh[cf * 66 + c8];
    d[0] = p0.x; d[1] = p0.y; d[2] = p1.x; d[3] = p1.y;
    d[4] = p2.x; d[5] = p2.y; d[6] = p3.x; d[7] = p3.y;
  }
  if (tid < 66)
    Ysh[tid * 66 + 64] = b2f(Y[(size_t)(tid * 64 + o) * BNP + ybase + 64]);
  const float* BtG = tf + TF_BT;
  for (int k = tid; k < 1056; k += 256)
    *(float4*)&Bt[4 * k] = *(const float4*)(BtG + 4 * k);
  if (tid < 32) einv[tid] = tf[TF_EINV + tid];
  __syncthreads();

  const int fl0 = 2 * (tid >> 3);
  const int j0 = 8 * (tid & 7);
  float a0[8], a1[8];
#pragma unroll
  for (int k = 0; k < 8; ++k) { a0[k] = 0.f; a1[k] = 0.f; }
#pragma unroll 6
  for (int cf = 0; cf < 66; ++cf) {
    const float2 av = *(const float2*)&Ysh[cf * 66 + fl0];
    const float4 b0 = *(const float4*)&Bt[cf * 64 + j0];
    const float4 b1 = *(const float4*)&Bt[cf * 64 + j0 + 4];
    const float bv[8] = {b0.x, b0.y, b0.z, b0.w, b1.x, b1.y, b1.z, b1.w};
#pragma unroll
    for (int k = 0; k < 8; ++k) {
      a0[k] = fmaf(av.x, bv[k], a0[k]);
      a1[k] = fmaf(av.y, bv[k], a1[k]);
    }
  }
  *(float4*)&Csh[fl0 * 68 + j0]           = make_float4(a0[0], a0[1], a0[2], a0[3]);
  *(float4*)&Csh[fl0 * 68 + j0 + 4]       = make_float4(a0[4], a0[5], a0[6], a0[7]);
  *(float4*)&Csh[(fl0 + 1) * 68 + j0]     = make_float4(a1[0], a1[1], a1[2], a1[3]);
  *(float4*)&Csh[(fl0 + 1) * 68 + j0 + 4] = make_float4(a1[4], a1[5], a1[6], a1[7]);
  if (tid < 32) {   // fl = 64 halo row, only j<32 read
    float s = 0.f;
#pragma unroll 6
    for (int cf = 0; cf < 66; ++cf)
      s = fmaf(Ysh[cf * 66 + 64], Bt[cf * 64 + tid], s);
    Csh[64 * 68 + tid] = s;
  }
  __syncthreads();

  const int q0 = 8 * tid;
  const int j2 = q0 & 31;
  const int fl2 = 1 + (q0 >> 5);
  const float4 lo0 = *(const float4*)&Csh[fl2 * 68 + j2];
  const float4 lo1 = *(const float4*)&Csh[fl2 * 68 + j2 + 4];
  const float4 hi0 = *(const float4*)&Csh[(fl2 - 1) * 68 + j2 + 32];
  const float4 hi1 = *(const float4*)&Csh[(fl2 - 1) * 68 + j2 + 36];
  float v[8] = {lo0.x + hi0.x, lo0.y + hi0.y, lo0.z + hi0.z, lo0.w + hi0.w,
                lo1.x + hi1.x, lo1.y + hi1.y, lo1.z + hi1.z, lo1.w + hi1.w};
#pragma unroll
  for (int k = 0; k < 8; ++k) v[k] *= einv[j2 + k];
  float* po = out + (size_t)(b * 64 + o) * TT + 32 * n0 + q0;
  *(float4*)po       = make_float4(v[0], v[1], v[2], v[3]);
  *(float4*)(po + 4) = make_float4(v[4], v[5], v[6], v[7]);
}

// ---------------------------------------------------------------------------
extern "C" void kernel_launch(void* const* d_in, const int* in_sizes, int n_in,
                              void* d_out, int out_size, void* d_ws, size_t ws_size,
                              hipStream_t stream) {
  const float* x  = (const float*)d_in[0];   // [8,64,16384]
  const float* wt = (const float*)d_in[1];   // [64,64,33]
  float* out = (float*)d_out;                // [8,64,16384]
  u16* U = (u16*)d_ws;                                        // 35.1 MB bf16
  u16* t16 = (u16*)((char*)d_ws + (size_t)66 * 64 * BNP * 2); // bf16 tables
  float* tf = (float*)(t16 + TAB_TOT);                        // fp32 tables

  dim3 blk(256);
  k0_tables<<<dim3(36),       blk, 0, stream>>>(wt, t16, tf);
  k1_stft  <<<dim3(8, 64, 8), blk, 0, stream>>>(x, t16, U);
  k1b_last <<<dim3(4, 8),     blk, 0, stream>>>(x, t16, U);
  k2_mix   <<<dim3(65, 33),   blk, 0, stream>>>(t16, U);
  k3_istft <<<dim3(8, 64, 8), blk, 0, stream>>>(U, tf, out);
}

// Round 7
// 155.056 us; speedup vs baseline: 2.0951x; 1.1133x over previous
//
#include <hip/hip_runtime.h>
#include <cstddef>

#define TT 16384
#define NFRAMES 513
#define NFP 520                 // frames per batch, padded
#define BNP (8 * NFP)           // 4160 = 65 * 64
#define PI32 0.09817477042468103870f   // pi/32

typedef unsigned int u32;
typedef unsigned short u16;
typedef __attribute__((ext_vector_type(8))) short bf16x8;
typedef __attribute__((ext_vector_type(4))) float f32x4;

// u16-table layout after U (35,143,680 B)
#define TAB_WBF 0                        // [33][64][72]
#define TAB_BM  (33 * 64 * 72)           // [80][72]   (STFT A-operand)
#define TAB_BTA (TAB_BM + 80 * 72)       // [64 j][104 cf] (iDFT A-operand, cf<66 real)
#define TAB_TOT (TAB_BTA + 64 * 104)
// f32 tables after that
#define TF_EINV 0                        // 32

__device__ __forceinline__ float b2f(u16 h) {
  union { u32 u; float f; } v; v.u = ((u32)h) << 16; return v.f;
}
__device__ __forceinline__ u16 f2b(float f) {
  union { float f; u32 u; } v; v.f = f;
  const u32 r = v.u + 0x7FFFu + ((v.u >> 16) & 1u);   // RNE
  return (u16)(r >> 16);
}
__device__ __forceinline__ u32 pack2(float a, float b) {
  return (u32)f2b(a) | ((u32)f2b(b) << 16);
}
__device__ __forceinline__ float2 b2x2(u32 u) {
  union { u32 u; float f; } lo, hi;
  lo.u = u << 16; hi.u = u & 0xFFFF0000u;
  return make_float2(lo.f, hi.f);
}

// ---------------------------------------------------------------------------
// K0: constant tables.
//  blocks 0..32: Wbf[f][o][i] bf16 (stride 72)
//  block 33    : Bm[fc 0..79][j 0..71] bf16 (STFT A-operand; row 64 = f=32)
//  block 34    : BtA[j 0..63][cf 0..103] bf16: cf<66 the full iDFT*win*scale
//                table (same formula as the verified fp32 Bt), cf>=66 zero.
//                Plus einv (fp32).
// ---------------------------------------------------------------------------
__global__ __launch_bounds__(256) void k0_tables(const float* __restrict__ W,
                                                 u16* __restrict__ t16,
                                                 float* __restrict__ tf) {
  const int b = blockIdx.x, tid = threadIdx.x;
  if (b < 33) {
    for (int idx = tid; idx < 64 * 72; idx += 256) {
      const int o = idx / 72, i = idx % 72;
      const float v = (i < 64) ? W[(size_t)(o * 64 + i) * 33 + b] : 0.f;
      t16[TAB_WBF + b * 64 * 72 + idx] = f2b(v);
    }
  } else if (b == 33) {
    for (int idx = tid; idx < 80 * 72; idx += 256) {
      const int fc = idx / 72, j = idx % 72;
      float v = 0.f;
      if (j < 64 && fc < 65) {
        const float wj = 0.5f * (1.0f - cosf((float)j * PI32));
        if (fc < 64) {
          const int f = fc >> 1;
          const float ang = (float)((f * j) & 63) * PI32;
          v = wj * ((fc & 1) ? -sinf(ang) : cosf(ang));
        } else {
          v = (j & 1) ? -wj : wj;   // f=32 real row
        }
      }
      t16[TAB_BM + idx] = f2b(v);
    }
  } else {   // b == 34
    for (int idx = tid; idx < 64 * 104; idx += 256) {
      const int j = idx / 104, cf = idx % 104;
      float v = 0.f;
      if (cf < 66) {
        const int f = cf >> 1;
        const float wj = 0.5f * (1.0f - cosf((float)j * PI32));
        const float sc = ((f == 0) || (f == 32)) ? 0.015625f : 0.03125f;
        const float ang = (float)((f * j) & 63) * PI32;
        v = wj * sc * ((cf & 1) ? -sinf(ang) : cosf(ang));
      }
      t16[TAB_BTA + idx] = f2b(v);
    }
    if (tid < 32) {
      const float c = cosf((float)tid * PI32);
      tf[TF_EINV + tid] = 2.0f / (1.0f + c * c);
    }
  }
}

// ---------------------------------------------------------------------------
// K1: STFT frames 0..511 via MFMA (verified in R5, unchanged).
// ---------------------------------------------------------------------------
__global__ __launch_bounds__(256) void k1_stft(const float* __restrict__ x,
                                               const u16* __restrict__ t16,
                                               u16* __restrict__ U) {
  const int tile = blockIdx.x;   // 0..7
  const int ch   = blockIdx.y;
  const int b    = blockIdx.z;
  const int F0 = tile * 64;
  const int tid = threadIdx.x;
  __shared__ __align__(16) u16 Bm[80 * 72];
  __shared__ __align__(16) u16 Awt[64 * 72];   // [fl][j] bf16 frames

  for (int k = tid; k < 720; k += 256)
    ((uint4*)Bm)[k] = ((const uint4*)(t16 + TAB_BM))[k];

  const float* xb = x + (size_t)(b * 64 + ch) * TT;
  if (tile == 0) {
    if (tid < 32) Awt[tid] = f2b(xb[32 - tid]);      // left reflect, frame 0
    for (int c = 8 + tid; c < 520; c += 256) {
      const float4 v = *(const float4*)(xb + 4 * c - 32);
      const uint2 pk = make_uint2(pack2(v.x, v.y), pack2(v.z, v.w));
      const int flb = c >> 3, jj = 4 * (c & 7);
      if (flb < 64) *(uint2*)&Awt[flb * 72 + jj] = pk;
      *(uint2*)&Awt[(flb - 1) * 72 + 32 + jj] = pk;
    }
  } else {
    const float* src = xb + 32 * F0 - 32;
    for (int c = tid; c < 520; c += 256) {
      const float4 v = *(const float4*)(src + 4 * c);
      const uint2 pk = make_uint2(pack2(v.x, v.y), pack2(v.z, v.w));
      const int flb = c >> 3, jj = 4 * (c & 7);
      if (flb < 64) *(uint2*)&Awt[flb * 72 + jj] = pk;
      if (flb >= 1) *(uint2*)&Awt[(flb - 1) * 72 + 32 + jj] = pk;
    }
  }
  __syncthreads();

  const int wave = tid >> 6, lane = tid & 63;
  const int n = lane & 15, quad = lane >> 4;

  bf16x8 bfr[4][2];
#pragma unroll
  for (int nt = 0; nt < 4; ++nt)
#pragma unroll
    for (int ks = 0; ks < 2; ++ks)
      bfr[nt][ks] = *(const bf16x8*)&Awt[(nt * 16 + n) * 72 + ks * 32 + quad * 8];

  const int bnb = b * NFP + F0;
  const int npass = (wave == 0) ? 2 : 1;
  for (int pass = 0; pass < npass; ++pass) {
    const int mt = pass ? 4 : wave;
    bf16x8 af[2];
#pragma unroll
    for (int ks = 0; ks < 2; ++ks)
      af[ks] = *(const bf16x8*)&Bm[(mt * 16 + n) * 72 + ks * 32 + quad * 8];
    f32x4 acc[4];
#pragma unroll
    for (int nt = 0; nt < 4; ++nt) acc[nt] = (f32x4){0.f, 0.f, 0.f, 0.f};
#pragma unroll
    for (int ks = 0; ks < 2; ++ks)
#pragma unroll
      for (int nt = 0; nt < 4; ++nt)
        acc[nt] = __builtin_amdgcn_mfma_f32_16x16x32_bf16(af[ks], bfr[nt][ks],
                                                          acc[nt], 0, 0, 0);
#pragma unroll
    for (int nt = 0; nt < 4; ++nt) {
      const int fl = nt * 16 + n;
#pragma unroll
      for (int r = 0; r < 4; ++r) {
        const int fc = mt * 16 + quad * 4 + r;
        if (fc < 66)
          U[(size_t)(fc * 64 + ch) * BNP + bnb + fl] = f2b(acc[nt][r]);
      }
    }
  }
}

// ---------------------------------------------------------------------------
// K1b: frame 512 (verified, unchanged).
// ---------------------------------------------------------------------------
__global__ __launch_bounds__(256) void k1b_last(const float* __restrict__ x,
                                                const u16* __restrict__ t16,
                                                u16* __restrict__ U) {
  const int cg = blockIdx.x;
  const int b  = blockIdx.y;
  const int tid = threadIdx.x;
  __shared__ float xe[16 * 65];
  __shared__ __align__(16) u16 Bsh[80 * 72];
  for (int k = tid; k < 720; k += 256)
    ((uint4*)Bsh)[k] = ((const uint4*)(t16 + TAB_BM))[k];
  for (int idx = tid; idx < 16 * 64; idx += 256) {
    const int c = idx >> 6, j = idx & 63;
    const int t = (j < 32) ? (16352 + j) : (16414 - j);
    xe[c * 65 + j] = x[(size_t)(b * 64 + 16 * cg + c) * TT + t];
  }
  __syncthreads();
  for (int idx = tid; idx < 66 * 16; idx += 256) {
    const int fc = idx >> 4, c = idx & 15;
    float s = 0.f;
#pragma unroll 8
    for (int j = 0; j < 64; ++j)
      s = fmaf(xe[c * 65 + j], b2f(Bsh[fc * 72 + j]), s);
    U[(size_t)(fc * 64 + 16 * cg + c) * BNP + b * NFP + 512] = f2b(s);
  }
}

// ---------------------------------------------------------------------------
// K2: channel mix via MFMA, IN PLACE over U (verified in R5, unchanged).
// ---------------------------------------------------------------------------
__global__ __launch_bounds__(256) void k2_mix(const u16* __restrict__ t16,
                                              u16* __restrict__ U) {
  const int f   = blockIdx.y;
  const int bn0 = blockIdx.x * 64;
  const int tid = threadIdx.x;
  __shared__ __align__(16) u16 Ut[2 * 64 * 72];   // [c][q][i swizzled]
  __shared__ __align__(16) u16 Wl[64 * 72];       // [o][i]

  for (int k = tid; k < 576; k += 256)
    ((uint4*)Wl)[k] = ((const uint4*)(t16 + TAB_WBF + f * 64 * 72))[k];

#pragma unroll
  for (int kk = 0; kk < 4; ++kk) {
    const int id = tid + kk * 256;
    const int c = id >> 9, rem = id & 511;
    const int i = rem >> 3, qc = rem & 7;
    const uint4 raw = *(const uint4*)(U + (size_t)((2 * f + c) * 64 + i) * BNP + bn0 + 8 * qc);
    const int col = (((i >> 3) ^ qc) << 3) + (i & 7);
    u16* base = &Ut[c * 4608 + col];
#pragma unroll
    for (int e = 0; e < 8; ++e) {
      const u32 w = ((const u32*)&raw)[e >> 1];
      base[(8 * qc + e) * 72] = (u16)((e & 1) ? (w >> 16) : (w & 0xFFFFu));
    }
  }
  __syncthreads();

  const int wave = tid >> 6, lane = tid & 63;
  const int n = lane & 15, quad = lane >> 4;
  const int mt = wave;

  bf16x8 af[2];
#pragma unroll
  for (int ks = 0; ks < 2; ++ks)
    af[ks] = *(const bf16x8*)&Wl[(mt * 16 + n) * 72 + ks * 32 + quad * 8];

  f32x4 acc[4][2];
#pragma unroll
  for (int nt = 0; nt < 4; ++nt)
#pragma unroll
    for (int c = 0; c < 2; ++c) acc[nt][c] = (f32x4){0.f, 0.f, 0.f, 0.f};

#pragma unroll
  for (int ks = 0; ks < 2; ++ks)
#pragma unroll
    for (int nt = 0; nt < 4; ++nt) {
      const int q = nt * 16 + n;
      const int chunk = (((ks << 2) + quad) ^ ((q >> 3) & 7)) << 3;
#pragma unroll
      for (int c = 0; c < 2; ++c) {
        const bf16x8 bf = *(const bf16x8*)&Ut[c * 4608 + q * 72 + chunk];
        acc[nt][c] = __builtin_amdgcn_mfma_f32_16x16x32_bf16(af[ks], bf,
                                                             acc[nt][c], 0, 0, 0);
      }
    }

#pragma unroll
  for (int nt = 0; nt < 4; ++nt) {
    const int q = bn0 + nt * 16 + n;
#pragma unroll
    for (int c = 0; c < 2; ++c)
#pragma unroll
      for (int r = 0; r < 4; ++r) {
        const int o = mt * 16 + quad * 4 + r;
        U[(size_t)((2 * f + c) * 64 + o) * BNP + q] = f2b(acc[nt][c][r]);
      }
  }
}

// ---------------------------------------------------------------------------
// K3: ISTFT via MFMA, K=96 (all 66 cf rows inside the GEMM -- exact replica
// of the verified R5 contraction; no special-cased rows).
//   C[j][fl] = sum_{cf<96} BtA[j][cf] * Yt[fl][cf]   (cf>=66 rows are zero)
// A = constant bf16 table; B = LDS-transposed Y tile (stride 104, 2-way-free
// fragment reads).  Yt k-columns 66..103 zero-filled (NaN safety: uninit LDS
// times the zero A-columns would give 0*NaN).  Plain OLA + einv epilogue.
// ---------------------------------------------------------------------------
__global__ __launch_bounds__(256) void k3_istft(const u16* __restrict__ Y,
                                                const u16* __restrict__ t16,
                                                const float* __restrict__ tf,
                                                float* __restrict__ out) {
  const int tile = blockIdx.x;   // 0..7
  const int o    = blockIdx.y;
  const int b    = blockIdx.z;
  const int n0 = tile * 64;
  const int tid = threadIdx.x;
  __shared__ __align__(16) u16 BtA[64 * 104];  // [j][cf]
  __shared__ __align__(16) u16 Yt[80 * 104];   // [fl][cf]
  __shared__ float Csh[65 * 68];               // [fl][j]
  __shared__ float einv[32];

  for (int k = tid; k < 832; k += 256)         // 64*104/8
    ((uint4*)BtA)[k] = ((const uint4*)(t16 + TAB_BTA))[k];

  // zero-fill Yt columns 66..103 (rows 0..79); staging below writes cols 0..65
  for (int id = tid; id < 1520; id += 256) {   // 80 rows * 19 u32
    const int row = id / 19, c = id % 19;
    *(u32*)&Yt[row * 104 + 66 + 2 * c] = 0u;
  }
  const size_t ybase = (size_t)b * NFP + n0;
  for (int id = tid; id < 594; id += 256) {    // 66 cf x 9 fl-octs
    const int cf = id / 9, oct = id % 9;       // oct 8 reads fl 64..71 (pad ok)
    const uint4 raw = *(const uint4*)(Y + (size_t)(cf * 64 + o) * BNP + ybase + oct * 8);
    const u16* s = (const u16*)&raw;
#pragma unroll
    for (int e = 0; e < 8; ++e) Yt[(oct * 8 + e) * 104 + cf] = s[e];
  }
  if (tid < 32) einv[tid] = tf[TF_EINV + tid];
  __syncthreads();

  const int wave = tid >> 6, lane = tid & 63;
  const int n = lane & 15, quad = lane >> 4;
  const int mt = wave;                         // j-tile

  bf16x8 af[3];
#pragma unroll
  for (int ks = 0; ks < 3; ++ks)
    af[ks] = *(const bf16x8*)&BtA[(mt * 16 + n) * 104 + ks * 32 + quad * 8];

  f32x4 acc[5];
#pragma unroll
  for (int nt = 0; nt < 5; ++nt) acc[nt] = (f32x4){0.f, 0.f, 0.f, 0.f};
#pragma unroll
  for (int ks = 0; ks < 3; ++ks)
#pragma unroll
    for (int nt = 0; nt < 5; ++nt) {
      const bf16x8 bf = *(const bf16x8*)&Yt[(nt * 16 + n) * 104 + ks * 32 + quad * 8];
      acc[nt] = __builtin_amdgcn_mfma_f32_16x16x32_bf16(af[ks], bf, acc[nt], 0, 0, 0);
    }
#pragma unroll
  for (int nt = 0; nt < 5; ++nt) {
    const int fl = nt * 16 + n;
    if (nt < 4 || n == 0)                      // fl <= 64
      *(float4*)&Csh[fl * 68 + mt * 16 + quad * 4] =
          make_float4(acc[nt][0], acc[nt][1], acc[nt][2], acc[nt][3]);
  }
  __syncthreads();

  // OLA: padded pos p = 32*(n0+1) + q; frames fl2 (low half) and fl2-1 (high)
  const int q0 = 8 * tid;
  const int j2 = q0 & 31;
  const int fl2 = 1 + (q0 >> 5);
  const float4 lo0 = *(const float4*)&Csh[fl2 * 68 + j2];
  const float4 lo1 = *(const float4*)&Csh[fl2 * 68 + j2 + 4];
  const float4 hi0 = *(const float4*)&Csh[(fl2 - 1) * 68 + j2 + 32];
  const float4 hi1 = *(const float4*)&Csh[(fl2 - 1) * 68 + j2 + 36];
  float v[8] = {lo0.x + hi0.x, lo0.y + hi0.y, lo0.z + hi0.z, lo0.w + hi0.w,
                lo1.x + hi1.x, lo1.y + hi1.y, lo1.z + hi1.z, lo1.w + hi1.w};
#pragma unroll
  for (int k = 0; k < 8; ++k) v[k] *= einv[j2 + k];
  float* po = out + (size_t)(b * 64 + o) * TT + 32 * n0 + q0;
  *(float4*)po       = make_float4(v[0], v[1], v[2], v[3]);
  *(float4*)(po + 4) = make_float4(v[4], v[5], v[6], v[7]);
}

// ---------------------------------------------------------------------------
extern "C" void kernel_launch(void* const* d_in, const int* in_sizes, int n_in,
                              void* d_out, int out_size, void* d_ws, size_t ws_size,
                              hipStream_t stream) {
  const float* x  = (const float*)d_in[0];   // [8,64,16384]
  const float* wt = (const float*)d_in[1];   // [64,64,33]
  float* out = (float*)d_out;                // [8,64,16384]
  u16* U = (u16*)d_ws;                                        // 35.1 MB bf16
  u16* t16 = (u16*)((char*)d_ws + (size_t)66 * 64 * BNP * 2); // bf16 tables
  float* tf = (float*)(t16 + TAB_TOT);                        // fp32 tables

  dim3 blk(256);
  k0_tables<<<dim3(35),       blk, 0, stream>>>(wt, t16, tf);
  k1_stft  <<<dim3(8, 64, 8), blk, 0, stream>>>(x, t16, U);
  k1b_last <<<dim3(4, 8),     blk, 0, stream>>>(x, t16, U);
  k2_mix   <<<dim3(65, 33),   blk, 0, stream>>>(t16, U);
  k3_istft <<<dim3(8, 64, 8), blk, 0, stream>>>(U, t16, tf, out);
}